// Round 1
// baseline (1135.838 us; speedup 1.0000x reference)
//
#include <hip/hip_runtime.h>
#include <math.h>

#define N_NODES 50000
#define N_EDGES 800000
#define EP (N_EDGES + N_NODES)   // edges incl. self loops
#define NEG_SLOPE 0.2f

// ---------- helpers ----------
__device__ __forceinline__ unsigned f2ord(float f) {
  unsigned u = __float_as_uint(f);
  return (u & 0x80000000u) ? ~u : (u | 0x80000000u);
}
__device__ __forceinline__ float ord2f(unsigned o) {
  unsigned u = (o & 0x80000000u) ? (o ^ 0x80000000u) : ~o;
  return __uint_as_float(u);
}

__global__ void fill_u32(unsigned* p, unsigned v, int n) {
  int i = blockIdx.x * blockDim.x + threadIdx.x;
  if (i < n) p[i] = v;
}

// ---------- self-loop attr (mean of incoming edge_attr) + degree histogram ----------
__global__ void loop_accum(const int* __restrict__ ei, const float* __restrict__ ea,
                           float* __restrict__ lattr, float* __restrict__ cnt,
                           int* __restrict__ deg) {
  int e = blockIdx.x * blockDim.x + threadIdx.x;
  if (e >= N_EDGES) return;
  int d = ei[N_EDGES + e];
  atomicAdd(&lattr[2 * d],     ea[2 * e]);
  atomicAdd(&lattr[2 * d + 1], ea[2 * e + 1]);
  atomicAdd(&cnt[d], 1.0f);
  atomicAdd(&deg[d], 1);
}

__global__ void loop_fin(float* lattr, const float* cnt) {
  int i = blockIdx.x * blockDim.x + threadIdx.x;
  if (i >= N_NODES) return;
  float c = fmaxf(cnt[i], 1.0f);
  lattr[2 * i]     /= c;
  lattr[2 * i + 1] /= c;
}

// ---------- CSR build: chunked single-block exclusive scan then scatter ----------
__global__ void scan_deg(const int* __restrict__ deg, int* __restrict__ rowptr,
                         int* __restrict__ cursor) {
  __shared__ int buf[2][1024];
  const int n = N_NODES;
  const int chunk = (n + 1023) / 1024;
  int lo = threadIdx.x * chunk;
  int hi = lo + chunk; if (hi > n) hi = n;
  int s = 0;
  for (int i = lo; i < hi; ++i) s += deg[i];
  buf[0][threadIdx.x] = s;
  __syncthreads();
  int cur = 0;
  for (int off = 1; off < 1024; off <<= 1) {
    int t = buf[cur][threadIdx.x];
    if ((int)threadIdx.x >= off) t += buf[cur][threadIdx.x - off];
    buf[cur ^ 1][threadIdx.x] = t;
    cur ^= 1;
    __syncthreads();
  }
  int excl = buf[cur][threadIdx.x] - s;
  int run = excl;
  for (int i = lo; i < hi; ++i) {
    rowptr[i] = run; cursor[i] = run;
    run += deg[i];
  }
  if (threadIdx.x == 1023) rowptr[n] = buf[cur][1023];
}

__global__ void scatter_edges(const int* __restrict__ ei, int* __restrict__ cursor,
                              int* __restrict__ srcs, int* __restrict__ eidx) {
  int e = blockIdx.x * blockDim.x + threadIdx.x;
  if (e >= EP) return;
  int s, d;
  if (e < N_EDGES) { s = ei[e]; d = ei[N_EDGES + e]; }
  else { s = d = e - N_EDGES; }
  int pos = atomicAdd(&cursor[d], 1);
  srcs[pos] = s;
  eidx[pos] = e;
}

// ---------- Ae[d][h] = sum_c We[d, h*128+c] * att_e[h,c]  (6 scalars) ----------
__global__ void prep_ae(const float* __restrict__ We1, const float* __restrict__ ae1,
                        const float* __restrict__ We2, const float* __restrict__ ae2,
                        float* __restrict__ Ae) {
  int b = blockIdx.x;
  int t = threadIdx.x;
  float s = 0.f;
  if (b < 4) {
    int d = b >> 1, h = b & 1;
    for (int c = t; c < 128; c += 64)
      s += We1[d * 256 + h * 128 + c] * ae1[h * 128 + c];
  } else {
    int d = b - 4;
    for (int c = t; c < 128; c += 64)
      s += We2[d * 128 + c] * ae2[c];
  }
  for (int off = 32; off > 0; off >>= 1) s += __shfl_down(s, off);
  if (t == 0) Ae[b] = s;   // layout: [d0h0, d0h1, d1h0, d1h1, d0(conv2), d1(conv2)]
}

// ---------- fp32 GEMM: C[M,N] = A[M,K] @ B[K,N], 128x128 tile, 8x8 micro ----------
#define BM 128
#define BN 128
#define BK 16
__global__ __launch_bounds__(256) void gemm_f32(const float* __restrict__ A,
                                                const float* __restrict__ B,
                                                float* __restrict__ C,
                                                int M, int N, int K) {
  __shared__ __attribute__((aligned(16))) float As[BK][BM + 4];
  __shared__ __attribute__((aligned(16))) float Bs[BK][BN + 4];
  int bm = blockIdx.y * BM, bn = blockIdx.x * BN;
  int tid = threadIdx.x;
  int tx = tid & 15, ty = tid >> 4;
  float acc[8][8] = {};
  for (int k0 = 0; k0 < K; k0 += BK) {
    #pragma unroll
    for (int l = tid; l < BM * BK; l += 256) {
      int m = l >> 4, kk = l & 15;
      int gm = bm + m;
      As[kk][m] = (gm < M) ? A[(size_t)gm * K + k0 + kk] : 0.f;
    }
    #pragma unroll
    for (int l = tid; l < BK * BN; l += 256) {
      int kk = l >> 7, nn = l & 127;
      Bs[kk][nn] = B[(size_t)(k0 + kk) * N + bn + nn];
    }
    __syncthreads();
    #pragma unroll
    for (int kk = 0; kk < BK; ++kk) {
      float4 a0 = *(const float4*)&As[kk][ty * 8];
      float4 a1 = *(const float4*)&As[kk][ty * 8 + 4];
      float4 b0 = *(const float4*)&Bs[kk][tx * 8];
      float4 b1 = *(const float4*)&Bs[kk][tx * 8 + 4];
      float av[8] = {a0.x, a0.y, a0.z, a0.w, a1.x, a1.y, a1.z, a1.w};
      float bv[8] = {b0.x, b0.y, b0.z, b0.w, b1.x, b1.y, b1.z, b1.w};
      #pragma unroll
      for (int i = 0; i < 8; ++i)
        #pragma unroll
        for (int j = 0; j < 8; ++j)
          acc[i][j] = fmaf(av[i], bv[j], acc[i][j]);
    }
    __syncthreads();
  }
  #pragma unroll
  for (int i = 0; i < 8; ++i) {
    int gm = bm + ty * 8 + i;
    if (gm >= M) continue;
    float4 v0 = {acc[i][0], acc[i][1], acc[i][2], acc[i][3]};
    float4 v1 = {acc[i][4], acc[i][5], acc[i][6], acc[i][7]};
    *(float4*)&C[(size_t)gm * N + bn + tx * 8] = v0;
    *(float4*)&C[(size_t)gm * N + bn + tx * 8 + 4] = v1;
  }
}

// ---------- per-node attention scalars: a_src/a_dst = sum_c xh*att ----------
template <int H>
__global__ void node_attn(const float* __restrict__ xh, const float* __restrict__ att_src,
                          const float* __restrict__ att_dst, float* __restrict__ asrc,
                          float* __restrict__ adst) {
  int n = blockIdx.x;
  int t = threadIdx.x;  // 0..63
  #pragma unroll
  for (int h = 0; h < H; ++h) {
    float v0 = xh[(size_t)n * (H * 128) + h * 128 + t];
    float v1 = xh[(size_t)n * (H * 128) + h * 128 + 64 + t];
    float ss = v0 * att_src[h * 128 + t] + v1 * att_src[h * 128 + 64 + t];
    float sd = v0 * att_dst[h * 128 + t] + v1 * att_dst[h * 128 + 64 + t];
    #pragma unroll
    for (int off = 32; off > 0; off >>= 1) {
      ss += __shfl_down(ss, off);
      sd += __shfl_down(sd, off);
    }
    if (t == 0) { asrc[n * H + h] = ss; adst[n * H + h] = sd; }
  }
}

// ---------- edge logits + segment max ----------
template <int H>
__global__ void edge_logits(const int* __restrict__ ei, const float* __restrict__ ea,
                            const float* __restrict__ lattr, const float* __restrict__ asrc,
                            const float* __restrict__ adst, const float* __restrict__ Ae,
                            float* __restrict__ elog, unsigned* __restrict__ nmax, int aeoff) {
  int e = blockIdx.x * blockDim.x + threadIdx.x;
  if (e >= EP) return;
  int s, d; float e0, e1;
  if (e < N_EDGES) { s = ei[e]; d = ei[N_EDGES + e]; e0 = ea[2 * e]; e1 = ea[2 * e + 1]; }
  else { s = d = e - N_EDGES; e0 = lattr[2 * s]; e1 = lattr[2 * s + 1]; }
  #pragma unroll
  for (int h = 0; h < H; ++h) {
    float l = asrc[s * H + h] + adst[d * H + h] + e0 * Ae[aeoff + h] + e1 * Ae[aeoff + H + h];
    l = (l > 0.f) ? l : NEG_SLOPE * l;
    elog[(size_t)e * H + h] = l;
    atomicMax(&nmax[d * H + h], f2ord(l));
  }
}

// ---------- exp(l - m) in place + segment sum ----------
template <int H>
__global__ void edge_exp(const int* __restrict__ ei, float* __restrict__ elog,
                         const unsigned* __restrict__ nmax, float* __restrict__ nsum) {
  int e = blockIdx.x * blockDim.x + threadIdx.x;
  if (e >= EP) return;
  int d = (e < N_EDGES) ? ei[N_EDGES + e] : e - N_EDGES;
  #pragma unroll
  for (int h = 0; h < H; ++h) {
    float l = elog[(size_t)e * H + h];
    float m = ord2f(nmax[d * H + h]);
    float xv = expf(l - m);
    elog[(size_t)e * H + h] = xv;
    atomicAdd(&nsum[d * H + h], xv);
  }
}

// ---------- CSR aggregation: out[n,:] = sum_in alpha * xh[src,:] (+bias, opt elu) ----------
template <int H, int ACT>
__global__ void aggregate(const float* __restrict__ xh, const float* __restrict__ ex,
                          const float* __restrict__ nsum, const int* __restrict__ rowptr,
                          const int* __restrict__ srcs, const int* __restrict__ eidx,
                          const float* __restrict__ bias, float* __restrict__ out) {
  int n = blockIdx.x;
  int t = threadIdx.x;          // 0 .. H*128-1
  int h = t >> 7;
  float inv = 1.0f / (nsum[n * H + h] + 1e-16f);
  int beg = rowptr[n], end = rowptr[n + 1];
  float acc = 0.f;
  for (int j = beg; j < end; ++j) {
    int s = srcs[j];
    int e = eidx[j];
    float a = ex[(size_t)e * H + h] * inv;
    acc = fmaf(a, xh[(size_t)s * (H * 128) + t], acc);
  }
  float v = acc + bias[t];
  if (ACT) v = (v > 0.f) ? v : expm1f(v);
  out[(size_t)n * (H * 128) + t] = v;
}

// ---------- launch ----------
extern "C" void kernel_launch(void* const* d_in, const int* in_sizes, int n_in,
                              void* d_out, int out_size, void* d_ws, size_t ws_size,
                              hipStream_t stream) {
  const float* x    = (const float*)d_in[0];
  const int*   ei   = (const int*)d_in[1];
  const float* ea   = (const float*)d_in[2];
  const float* W1   = (const float*)d_in[3];
  const float* as1  = (const float*)d_in[4];
  const float* ad1  = (const float*)d_in[5];
  const float* We1  = (const float*)d_in[6];
  const float* ae1  = (const float*)d_in[7];
  const float* b1   = (const float*)d_in[8];
  const float* W2   = (const float*)d_in[9];
  const float* as2  = (const float*)d_in[10];
  const float* ad2  = (const float*)d_in[11];
  const float* We2  = (const float*)d_in[12];
  const float* ae2  = (const float*)d_in[13];
  const float* b2   = (const float*)d_in[14];
  float* out = (float*)d_out;

  char* w = (char*)d_ws;
  size_t off = 0;
  auto alloc = [&](size_t bytes) -> void* {
    void* p = w + off;
    off = (off + bytes + 255) & ~(size_t)255;
    return p;
  };
  float*    xh     = (float*)alloc((size_t)N_NODES * 256 * 4);
  float*    hbuf   = (float*)alloc((size_t)N_NODES * 256 * 4);
  float*    elog   = (float*)alloc((size_t)EP * 2 * 4);
  int*      rowptr = (int*)alloc((N_NODES + 1) * 4);
  int*      cursor = (int*)alloc(N_NODES * 4);
  int*      deg    = (int*)alloc(N_NODES * 4);
  int*      srcs   = (int*)alloc((size_t)EP * 4);
  int*      eidx   = (int*)alloc((size_t)EP * 4);
  float*    asrc   = (float*)alloc(N_NODES * 2 * 4);
  float*    adst   = (float*)alloc(N_NODES * 2 * 4);
  unsigned* nmax   = (unsigned*)alloc(N_NODES * 2 * 4);
  float*    nsum   = (float*)alloc(N_NODES * 2 * 4);
  float*    lattr  = (float*)alloc(N_NODES * 2 * 4);
  float*    cnt    = (float*)alloc(N_NODES * 4);
  float*    Ae     = (float*)alloc(16 * 4);

  const unsigned ORDNEGINF = 0x007FFFFFu;
  auto cdiv = [](int a, int b) { return (a + b - 1) / b; };

  // init
  fill_u32<<<cdiv(N_NODES * 2, 256), 256, 0, stream>>>((unsigned*)lattr, 0u, N_NODES * 2);
  fill_u32<<<cdiv(N_NODES, 256), 256, 0, stream>>>((unsigned*)cnt, 0u, N_NODES);
  fill_u32<<<cdiv(N_NODES, 256), 256, 0, stream>>>((unsigned*)deg, 1u, N_NODES); // self loop
  fill_u32<<<cdiv(N_NODES * 2, 256), 256, 0, stream>>>(nmax, ORDNEGINF, N_NODES * 2);
  fill_u32<<<cdiv(N_NODES * 2, 256), 256, 0, stream>>>((unsigned*)nsum, 0u, N_NODES * 2);

  // graph prep
  loop_accum<<<cdiv(N_EDGES, 256), 256, 0, stream>>>(ei, ea, lattr, cnt, deg);
  loop_fin<<<cdiv(N_NODES, 256), 256, 0, stream>>>(lattr, cnt);
  scan_deg<<<1, 1024, 0, stream>>>(deg, rowptr, cursor);
  scatter_edges<<<cdiv(EP, 256), 256, 0, stream>>>(ei, cursor, srcs, eidx);
  prep_ae<<<6, 64, 0, stream>>>(We1, ae1, We2, ae2, Ae);

  // ---- conv1 (H=2, C=128) ----
  gemm_f32<<<dim3(2, cdiv(N_NODES, BM)), 256, 0, stream>>>(x, W1, xh, N_NODES, 256, 256);
  node_attn<2><<<N_NODES, 64, 0, stream>>>(xh, as1, ad1, asrc, adst);
  edge_logits<2><<<cdiv(EP, 256), 256, 0, stream>>>(ei, ea, lattr, asrc, adst, Ae, elog, nmax, 0);
  edge_exp<2><<<cdiv(EP, 256), 256, 0, stream>>>(ei, elog, nmax, nsum);
  aggregate<2, 1><<<N_NODES, 256, 0, stream>>>(xh, elog, nsum, rowptr, srcs, eidx, b1, hbuf);

  // ---- conv2 (H=1, C=128) ----
  fill_u32<<<cdiv(N_NODES, 256), 256, 0, stream>>>(nmax, ORDNEGINF, N_NODES);
  fill_u32<<<cdiv(N_NODES, 256), 256, 0, stream>>>((unsigned*)nsum, 0u, N_NODES);
  gemm_f32<<<dim3(1, cdiv(N_NODES, BM)), 256, 0, stream>>>(hbuf, W2, xh, N_NODES, 128, 256);
  node_attn<1><<<N_NODES, 64, 0, stream>>>(xh, as2, ad2, asrc, adst);
  edge_logits<1><<<cdiv(EP, 256), 256, 0, stream>>>(ei, ea, lattr, asrc, adst, Ae, elog, nmax, 4);
  edge_exp<1><<<cdiv(EP, 256), 256, 0, stream>>>(ei, elog, nmax, nsum);
  aggregate<1, 0><<<N_NODES, 128, 0, stream>>>(xh, elog, nsum, rowptr, srcs, eidx, b2, out);
}

// Round 2
// 1017.209 us; speedup vs baseline: 1.1166x; 1.1166x over previous
//
#include <hip/hip_runtime.h>
#include <math.h>

#define N_NODES 50000
#define N_EDGES 800000
#define EP (N_EDGES + N_NODES)   // edges incl. self loops
#define NEG_SLOPE 0.2f

// ---------- helpers ----------
__device__ __forceinline__ unsigned f2ord(float f) {
  unsigned u = __float_as_uint(f);
  return (u & 0x80000000u) ? ~u : (u | 0x80000000u);
}
__device__ __forceinline__ float ord2f(unsigned o) {
  unsigned u = (o & 0x80000000u) ? (o ^ 0x80000000u) : ~o;
  return __uint_as_float(u);
}

__global__ void fill_u32(unsigned* p, unsigned v, int n) {
  int i = blockIdx.x * blockDim.x + threadIdx.x;
  if (i < n) p[i] = v;
}

// ---------- self-loop attr (mean of incoming edge_attr) + degree histogram ----------
__global__ void loop_accum(const int* __restrict__ ei, const float* __restrict__ ea,
                           float* __restrict__ lattr, float* __restrict__ cnt,
                           int* __restrict__ deg) {
  int e = blockIdx.x * blockDim.x + threadIdx.x;
  if (e >= N_EDGES) return;
  int d = ei[N_EDGES + e];
  atomicAdd(&lattr[2 * d],     ea[2 * e]);
  atomicAdd(&lattr[2 * d + 1], ea[2 * e + 1]);
  atomicAdd(&cnt[d], 1.0f);
  atomicAdd(&deg[d], 1);
}

__global__ void loop_fin(float* lattr, const float* cnt) {
  int i = blockIdx.x * blockDim.x + threadIdx.x;
  if (i >= N_NODES) return;
  float c = fmaxf(cnt[i], 1.0f);
  lattr[2 * i]     /= c;
  lattr[2 * i + 1] /= c;
}

// ---------- CSR build: chunked single-block exclusive scan then scatter ----------
__global__ void scan_deg(const int* __restrict__ deg, int* __restrict__ rowptr,
                         int* __restrict__ cursor) {
  __shared__ int buf[2][1024];
  const int n = N_NODES;
  const int chunk = (n + 1023) / 1024;
  int lo = threadIdx.x * chunk;
  int hi = lo + chunk; if (hi > n) hi = n;
  int s = 0;
  for (int i = lo; i < hi; ++i) s += deg[i];
  buf[0][threadIdx.x] = s;
  __syncthreads();
  int cur = 0;
  for (int off = 1; off < 1024; off <<= 1) {
    int t = buf[cur][threadIdx.x];
    if ((int)threadIdx.x >= off) t += buf[cur][threadIdx.x - off];
    buf[cur ^ 1][threadIdx.x] = t;
    cur ^= 1;
    __syncthreads();
  }
  int excl = buf[cur][threadIdx.x] - s;
  int run = excl;
  for (int i = lo; i < hi; ++i) {
    rowptr[i] = run; cursor[i] = run;
    run += deg[i];
  }
  if (threadIdx.x == 1023) rowptr[n] = buf[cur][1023];
}

// also emits dsts[] per CSR slot and the inverse permutation epos[e] -> slot
__global__ void scatter_edges(const int* __restrict__ ei, int* __restrict__ cursor,
                              int* __restrict__ srcs, int* __restrict__ dsts,
                              int* __restrict__ epos) {
  int e = blockIdx.x * blockDim.x + threadIdx.x;
  if (e >= EP) return;
  int s, d;
  if (e < N_EDGES) { s = ei[e]; d = ei[N_EDGES + e]; }
  else { s = d = e - N_EDGES; }
  int pos = atomicAdd(&cursor[d], 1);
  srcs[pos] = s;
  dsts[pos] = d;
  epos[e] = pos;
}

// ---------- Ae[d][h] = sum_c We[d, h*128+c] * att_e[h,c]  (6 scalars) ----------
__global__ void prep_ae(const float* __restrict__ We1, const float* __restrict__ ae1,
                        const float* __restrict__ We2, const float* __restrict__ ae2,
                        float* __restrict__ Ae) {
  int b = blockIdx.x;
  int t = threadIdx.x;
  float s = 0.f;
  if (b < 4) {
    int d = b >> 1, h = b & 1;
    for (int c = t; c < 128; c += 64)
      s += We1[d * 256 + h * 128 + c] * ae1[h * 128 + c];
  } else {
    int d = b - 4;
    for (int c = t; c < 128; c += 64)
      s += We2[d * 128 + c] * ae2[c];
  }
  for (int off = 32; off > 0; off >>= 1) s += __shfl_down(s, off);
  if (t == 0) Ae[b] = s;   // layout: [d0h0, d0h1, d1h0, d1h1, d0(conv2), d1(conv2)]
}

// ---------- fp32 GEMM: C[M,N] = A[M,K] @ B[K,N], 128x128 tile, 8x8 micro ----------
#define BM 128
#define BN 128
#define BK 16
__global__ __launch_bounds__(256) void gemm_f32(const float* __restrict__ A,
                                                const float* __restrict__ B,
                                                float* __restrict__ C,
                                                int M, int N, int K) {
  __shared__ __attribute__((aligned(16))) float As[BK][BM + 4];
  __shared__ __attribute__((aligned(16))) float Bs[BK][BN + 4];
  int bm = blockIdx.y * BM, bn = blockIdx.x * BN;
  int tid = threadIdx.x;
  int tx = tid & 15, ty = tid >> 4;
  float acc[8][8] = {};
  for (int k0 = 0; k0 < K; k0 += BK) {
    #pragma unroll
    for (int l = tid; l < BM * BK; l += 256) {
      int m = l >> 4, kk = l & 15;
      int gm = bm + m;
      As[kk][m] = (gm < M) ? A[(size_t)gm * K + k0 + kk] : 0.f;
    }
    #pragma unroll
    for (int l = tid; l < BK * BN; l += 256) {
      int kk = l >> 7, nn = l & 127;
      Bs[kk][nn] = B[(size_t)(k0 + kk) * N + bn + nn];
    }
    __syncthreads();
    #pragma unroll
    for (int kk = 0; kk < BK; ++kk) {
      float4 a0 = *(const float4*)&As[kk][ty * 8];
      float4 a1 = *(const float4*)&As[kk][ty * 8 + 4];
      float4 b0 = *(const float4*)&Bs[kk][tx * 8];
      float4 b1 = *(const float4*)&Bs[kk][tx * 8 + 4];
      float av[8] = {a0.x, a0.y, a0.z, a0.w, a1.x, a1.y, a1.z, a1.w};
      float bv[8] = {b0.x, b0.y, b0.z, b0.w, b1.x, b1.y, b1.z, b1.w};
      #pragma unroll
      for (int i = 0; i < 8; ++i)
        #pragma unroll
        for (int j = 0; j < 8; ++j)
          acc[i][j] = fmaf(av[i], bv[j], acc[i][j]);
    }
    __syncthreads();
  }
  #pragma unroll
  for (int i = 0; i < 8; ++i) {
    int gm = bm + ty * 8 + i;
    if (gm >= M) continue;
    float4 v0 = {acc[i][0], acc[i][1], acc[i][2], acc[i][3]};
    float4 v1 = {acc[i][4], acc[i][5], acc[i][6], acc[i][7]};
    *(float4*)&C[(size_t)gm * N + bn + tx * 8] = v0;
    *(float4*)&C[(size_t)gm * N + bn + tx * 8 + 4] = v1;
  }
}

// ---------- per-node attention scalars: a_src/a_dst = sum_c xh*att ----------
template <int H>
__global__ void node_attn(const float* __restrict__ xh, const float* __restrict__ att_src,
                          const float* __restrict__ att_dst, float* __restrict__ asrc,
                          float* __restrict__ adst) {
  int n = blockIdx.x;
  int t = threadIdx.x;  // 0..63
  #pragma unroll
  for (int h = 0; h < H; ++h) {
    float v0 = xh[(size_t)n * (H * 128) + h * 128 + t];
    float v1 = xh[(size_t)n * (H * 128) + h * 128 + 64 + t];
    float ss = v0 * att_src[h * 128 + t] + v1 * att_src[h * 128 + 64 + t];
    float sd = v0 * att_dst[h * 128 + t] + v1 * att_dst[h * 128 + 64 + t];
    #pragma unroll
    for (int off = 32; off > 0; off >>= 1) {
      ss += __shfl_down(ss, off);
      sd += __shfl_down(sd, off);
    }
    if (t == 0) { asrc[n * H + h] = ss; adst[n * H + h] = sd; }
  }
}

// ---------- edge logits (written to CSR slot order) + segment max ----------
template <int H>
__global__ void edge_logits(const int* __restrict__ ei, const float* __restrict__ ea,
                            const float* __restrict__ lattr, const float* __restrict__ asrc,
                            const float* __restrict__ adst, const float* __restrict__ Ae,
                            const int* __restrict__ epos,
                            float* __restrict__ elog, unsigned* __restrict__ nmax, int aeoff) {
  int e = blockIdx.x * blockDim.x + threadIdx.x;
  if (e >= EP) return;
  int s, d; float e0, e1;
  if (e < N_EDGES) { s = ei[e]; d = ei[N_EDGES + e]; e0 = ea[2 * e]; e1 = ea[2 * e + 1]; }
  else { s = d = e - N_EDGES; e0 = lattr[2 * s]; e1 = lattr[2 * s + 1]; }
  int pos = epos[e];
  #pragma unroll
  for (int h = 0; h < H; ++h) {
    float l = asrc[s * H + h] + adst[d * H + h] + e0 * Ae[aeoff + h] + e1 * Ae[aeoff + H + h];
    l = (l > 0.f) ? l : NEG_SLOPE * l;
    elog[(size_t)pos * H + h] = l;
    atomicMax(&nmax[d * H + h], f2ord(l));
  }
}

// ---------- exp(l - m) in place (slot-parallel, sequential) + segment sum ----------
template <int H>
__global__ void edge_exp(const int* __restrict__ dsts, float* __restrict__ elog,
                         const unsigned* __restrict__ nmax, float* __restrict__ nsum) {
  int i = blockIdx.x * blockDim.x + threadIdx.x;
  if (i >= EP) return;
  int d = dsts[i];
  #pragma unroll
  for (int h = 0; h < H; ++h) {
    float l = elog[(size_t)i * H + h];
    float m = ord2f(nmax[d * H + h]);
    float xv = expf(l - m);
    elog[(size_t)i * H + h] = xv;
    atomicAdd(&nsum[d * H + h], xv);
  }
}

// ---------- CSR aggregation: out[n,:] = inv * sum_in ex * xh[src,:] (+bias, opt elu) ----
// 4-way unrolled: 4 independent row-gathers in flight per wave.
template <int H, int ACT>
__global__ void aggregate(const float* __restrict__ xh, const float* __restrict__ ex,
                          const float* __restrict__ nsum, const int* __restrict__ rowptr,
                          const int* __restrict__ srcs, const float* __restrict__ bias,
                          float* __restrict__ out) {
  int n = blockIdx.x;
  int t = threadIdx.x;          // 0 .. H*128-1
  int h = t >> 7;
  float inv = 1.0f / (nsum[n * H + h] + 1e-16f);
  int beg = rowptr[n], end = rowptr[n + 1];
  float acc0 = 0.f, acc1 = 0.f, acc2 = 0.f, acc3 = 0.f;
  int j = beg;
  for (; j + 4 <= end; j += 4) {
    int s0 = srcs[j], s1 = srcs[j + 1], s2 = srcs[j + 2], s3 = srcs[j + 3];
    float a0 = ex[(size_t)j * H + h];
    float a1 = ex[(size_t)(j + 1) * H + h];
    float a2 = ex[(size_t)(j + 2) * H + h];
    float a3 = ex[(size_t)(j + 3) * H + h];
    acc0 = fmaf(a0, xh[(size_t)s0 * (H * 128) + t], acc0);
    acc1 = fmaf(a1, xh[(size_t)s1 * (H * 128) + t], acc1);
    acc2 = fmaf(a2, xh[(size_t)s2 * (H * 128) + t], acc2);
    acc3 = fmaf(a3, xh[(size_t)s3 * (H * 128) + t], acc3);
  }
  for (; j < end; ++j) {
    acc0 = fmaf(ex[(size_t)j * H + h], xh[(size_t)srcs[j] * (H * 128) + t], acc0);
  }
  float v = fmaf(inv, (acc0 + acc1) + (acc2 + acc3), bias[t]);
  if (ACT) v = (v > 0.f) ? v : expm1f(v);
  out[(size_t)n * (H * 128) + t] = v;
}

// ---------- launch ----------
extern "C" void kernel_launch(void* const* d_in, const int* in_sizes, int n_in,
                              void* d_out, int out_size, void* d_ws, size_t ws_size,
                              hipStream_t stream) {
  const float* x    = (const float*)d_in[0];
  const int*   ei   = (const int*)d_in[1];
  const float* ea   = (const float*)d_in[2];
  const float* W1   = (const float*)d_in[3];
  const float* as1  = (const float*)d_in[4];
  const float* ad1  = (const float*)d_in[5];
  const float* We1  = (const float*)d_in[6];
  const float* ae1  = (const float*)d_in[7];
  const float* b1   = (const float*)d_in[8];
  const float* W2   = (const float*)d_in[9];
  const float* as2  = (const float*)d_in[10];
  const float* ad2  = (const float*)d_in[11];
  const float* We2  = (const float*)d_in[12];
  const float* ae2  = (const float*)d_in[13];
  const float* b2   = (const float*)d_in[14];
  float* out = (float*)d_out;

  char* w = (char*)d_ws;
  size_t off = 0;
  auto alloc = [&](size_t bytes) -> void* {
    void* p = w + off;
    off = (off + bytes + 255) & ~(size_t)255;
    return p;
  };
  float*    xh     = (float*)alloc((size_t)N_NODES * 256 * 4);
  float*    hbuf   = (float*)alloc((size_t)N_NODES * 256 * 4);
  float*    elog   = (float*)alloc((size_t)EP * 2 * 4);
  int*      rowptr = (int*)alloc((N_NODES + 1) * 4);
  int*      cursor = (int*)alloc(N_NODES * 4);
  int*      deg    = (int*)alloc(N_NODES * 4);
  int*      srcs   = (int*)alloc((size_t)EP * 4);
  int*      dsts   = (int*)alloc((size_t)EP * 4);
  int*      epos   = (int*)alloc((size_t)EP * 4);
  float*    asrc   = (float*)alloc(N_NODES * 2 * 4);
  float*    adst   = (float*)alloc(N_NODES * 2 * 4);
  unsigned* nmax   = (unsigned*)alloc(N_NODES * 2 * 4);
  float*    nsum   = (float*)alloc(N_NODES * 2 * 4);
  float*    lattr  = (float*)alloc(N_NODES * 2 * 4);
  float*    cnt    = (float*)alloc(N_NODES * 4);
  float*    Ae     = (float*)alloc(16 * 4);

  const unsigned ORDNEGINF = 0x007FFFFFu;
  auto cdiv = [](int a, int b) { return (a + b - 1) / b; };

  // init
  fill_u32<<<cdiv(N_NODES * 2, 256), 256, 0, stream>>>((unsigned*)lattr, 0u, N_NODES * 2);
  fill_u32<<<cdiv(N_NODES, 256), 256, 0, stream>>>((unsigned*)cnt, 0u, N_NODES);
  fill_u32<<<cdiv(N_NODES, 256), 256, 0, stream>>>((unsigned*)deg, 1u, N_NODES); // self loop
  fill_u32<<<cdiv(N_NODES * 2, 256), 256, 0, stream>>>(nmax, ORDNEGINF, N_NODES * 2);
  fill_u32<<<cdiv(N_NODES * 2, 256), 256, 0, stream>>>((unsigned*)nsum, 0u, N_NODES * 2);

  // graph prep
  loop_accum<<<cdiv(N_EDGES, 256), 256, 0, stream>>>(ei, ea, lattr, cnt, deg);
  loop_fin<<<cdiv(N_NODES, 256), 256, 0, stream>>>(lattr, cnt);
  scan_deg<<<1, 1024, 0, stream>>>(deg, rowptr, cursor);
  scatter_edges<<<cdiv(EP, 256), 256, 0, stream>>>(ei, cursor, srcs, dsts, epos);
  prep_ae<<<6, 64, 0, stream>>>(We1, ae1, We2, ae2, Ae);

  // ---- conv1 (H=2, C=128) ----
  gemm_f32<<<dim3(2, cdiv(N_NODES, BM)), 256, 0, stream>>>(x, W1, xh, N_NODES, 256, 256);
  node_attn<2><<<N_NODES, 64, 0, stream>>>(xh, as1, ad1, asrc, adst);
  edge_logits<2><<<cdiv(EP, 256), 256, 0, stream>>>(ei, ea, lattr, asrc, adst, Ae, epos, elog, nmax, 0);
  edge_exp<2><<<cdiv(EP, 256), 256, 0, stream>>>(dsts, elog, nmax, nsum);
  aggregate<2, 1><<<N_NODES, 256, 0, stream>>>(xh, elog, nsum, rowptr, srcs, b1, hbuf);

  // ---- conv2 (H=1, C=128) ----
  fill_u32<<<cdiv(N_NODES, 256), 256, 0, stream>>>(nmax, ORDNEGINF, N_NODES);
  fill_u32<<<cdiv(N_NODES, 256), 256, 0, stream>>>((unsigned*)nsum, 0u, N_NODES);
  gemm_f32<<<dim3(1, cdiv(N_NODES, BM)), 256, 0, stream>>>(hbuf, W2, xh, N_NODES, 128, 256);
  node_attn<1><<<N_NODES, 64, 0, stream>>>(xh, as2, ad2, asrc, adst);
  edge_logits<1><<<cdiv(EP, 256), 256, 0, stream>>>(ei, ea, lattr, asrc, adst, Ae, epos, elog, nmax, 4);
  edge_exp<1><<<cdiv(EP, 256), 256, 0, stream>>>(dsts, elog, nmax, nsum);
  aggregate<1, 0><<<N_NODES, 128, 0, stream>>>(xh, elog, nsum, rowptr, srcs, b2, out);
}

// Round 3
// 876.307 us; speedup vs baseline: 1.2962x; 1.1608x over previous
//
#include <hip/hip_runtime.h>
#include <math.h>

#define N_NODES 50000
#define N_EDGES 800000
#define EP (N_EDGES + N_NODES)   // edges incl. self loops
#define NEG_SLOPE 0.2f

typedef __attribute__((ext_vector_type(8))) short bf16x8;
typedef __attribute__((ext_vector_type(4))) float f32x4;

// ---------- helpers ----------
__device__ __forceinline__ unsigned f2ord(float f) {
  unsigned u = __float_as_uint(f);
  return (u & 0x80000000u) ? ~u : (u | 0x80000000u);
}
__device__ __forceinline__ float ord2f(unsigned o) {
  unsigned u = (o & 0x80000000u) ? (o ^ 0x80000000u) : ~o;
  return __uint_as_float(u);
}
__device__ __forceinline__ unsigned short f2bf(float f) {
  unsigned u = __float_as_uint(f);
  unsigned r = (u + 0x7FFFu + ((u >> 16) & 1u)) >> 16;
  return (unsigned short)r;
}
__device__ __forceinline__ float bf2f(unsigned short b) {
  return __uint_as_float(((unsigned)b) << 16);
}

__global__ void fill_u32(unsigned* p, unsigned v, int n) {
  int i = blockIdx.x * blockDim.x + threadIdx.x;
  if (i < n) p[i] = v;
}

// ---------- self-loop attr (mean of incoming edge_attr) + degree histogram ----------
__global__ void loop_accum(const int* __restrict__ ei, const float* __restrict__ ea,
                           float* __restrict__ lattr, float* __restrict__ cnt,
                           int* __restrict__ deg) {
  int e = blockIdx.x * blockDim.x + threadIdx.x;
  if (e >= N_EDGES) return;
  int d = ei[N_EDGES + e];
  atomicAdd(&lattr[2 * d],     ea[2 * e]);
  atomicAdd(&lattr[2 * d + 1], ea[2 * e + 1]);
  atomicAdd(&cnt[d], 1.0f);
  atomicAdd(&deg[d], 1);
}

__global__ void loop_fin(float* lattr, const float* cnt) {
  int i = blockIdx.x * blockDim.x + threadIdx.x;
  if (i >= N_NODES) return;
  float c = fmaxf(cnt[i], 1.0f);
  lattr[2 * i]     /= c;
  lattr[2 * i + 1] /= c;
}

// ---------- CSR build ----------
__global__ void scan_deg(const int* __restrict__ deg, int* __restrict__ rowptr,
                         int* __restrict__ cursor) {
  __shared__ int buf[2][1024];
  const int n = N_NODES;
  const int chunk = (n + 1023) / 1024;
  int lo = threadIdx.x * chunk;
  int hi = lo + chunk; if (hi > n) hi = n;
  int s = 0;
  for (int i = lo; i < hi; ++i) s += deg[i];
  buf[0][threadIdx.x] = s;
  __syncthreads();
  int cur = 0;
  for (int off = 1; off < 1024; off <<= 1) {
    int t = buf[cur][threadIdx.x];
    if ((int)threadIdx.x >= off) t += buf[cur][threadIdx.x - off];
    buf[cur ^ 1][threadIdx.x] = t;
    cur ^= 1;
    __syncthreads();
  }
  int excl = buf[cur][threadIdx.x] - s;
  int run = excl;
  for (int i = lo; i < hi; ++i) {
    rowptr[i] = run; cursor[i] = run;
    run += deg[i];
  }
  if (threadIdx.x == 1023) rowptr[n] = buf[cur][1023];
}

__global__ void scatter_edges(const int* __restrict__ ei, int* __restrict__ cursor,
                              int* __restrict__ srcs, int* __restrict__ dsts,
                              int* __restrict__ epos) {
  int e = blockIdx.x * blockDim.x + threadIdx.x;
  if (e >= EP) return;
  int s, d;
  if (e < N_EDGES) { s = ei[e]; d = ei[N_EDGES + e]; }
  else { s = d = e - N_EDGES; }
  int pos = atomicAdd(&cursor[d], 1);
  srcs[pos] = s;
  dsts[pos] = d;
  epos[e] = pos;
}

// ---------- Ae[d][h] = sum_c We[d, h*128+c] * att_e[h,c] ----------
__global__ void prep_ae(const float* __restrict__ We1, const float* __restrict__ ae1,
                        const float* __restrict__ We2, const float* __restrict__ ae2,
                        float* __restrict__ Ae) {
  int b = blockIdx.x;
  int t = threadIdx.x;
  float s = 0.f;
  if (b < 4) {
    int d = b >> 1, h = b & 1;
    for (int c = t; c < 128; c += 64)
      s += We1[d * 256 + h * 128 + c] * ae1[h * 128 + c];
  } else {
    int d = b - 4;
    for (int c = t; c < 128; c += 64)
      s += We2[d * 128 + c] * ae2[c];
  }
  for (int off = 32; off > 0; off >>= 1) s += __shfl_down(s, off);
  if (t == 0) Ae[b] = s;   // [d0h0, d0h1, d1h0, d1h1, d0(conv2), d1(conv2)]
}

// ---------- fp32 -> bf16 hi/lo split (elementwise, float4 vectorized) ----------
__global__ void split_f32(const float* __restrict__ in, unsigned short* __restrict__ hi,
                          unsigned short* __restrict__ lo, int n4) {
  int i = blockIdx.x * blockDim.x + threadIdx.x;
  if (i >= n4) return;
  float4 v = ((const float4*)in)[i];
  ushort4 h, l;
  h.x = f2bf(v.x); l.x = f2bf(v.x - bf2f(h.x));
  h.y = f2bf(v.y); l.y = f2bf(v.y - bf2f(h.y));
  h.z = f2bf(v.z); l.z = f2bf(v.z - bf2f(h.z));
  h.w = f2bf(v.w); l.w = f2bf(v.w - bf2f(h.w));
  ((ushort4*)hi)[i] = h;
  ((ushort4*)lo)[i] = l;
}

// ---------- W -> W^T hi/lo split (tiny, cached) ----------
__global__ void bt_split(const float* __restrict__ W1, const float* __restrict__ W2,
                         unsigned short* __restrict__ b1h, unsigned short* __restrict__ b1l,
                         unsigned short* __restrict__ b2h, unsigned short* __restrict__ b2l) {
  int n = blockIdx.x;
  int k = threadIdx.x;   // 256
  float v; unsigned short* ph; unsigned short* pl; int idx;
  if (n < 256) { v = W1[k * 256 + n];       ph = b1h; pl = b1l; idx = n * 256 + k; }
  else         { v = W2[k * 128 + (n - 256)]; ph = b2h; pl = b2l; idx = (n - 256) * 256 + k; }
  unsigned short h = f2bf(v);
  ph[idx] = h;
  pl[idx] = f2bf(v - bf2f(h));
}

// ---------- split-bf16 MFMA GEMM: C[M,N] = A[M,256] @ B[256,N] (fp32-accurate) ----
// A given as hi/lo bf16 [M][256]; B given as B^T hi/lo bf16 [N][256].
// Block tile 64x128, BK=32, 4 waves (2x2), wave tile 32x64 (2x4 16x16 frags).
__global__ __launch_bounds__(256) void gemm_split(
    const unsigned short* __restrict__ Ahi, const unsigned short* __restrict__ Alo,
    const unsigned short* __restrict__ Bth, const unsigned short* __restrict__ Btl,
    float* __restrict__ C, int M, int N) {
  __shared__ __attribute__((aligned(16))) unsigned short As[2][64][40];
  __shared__ __attribute__((aligned(16))) unsigned short Bs[2][128][40];
  int bm = blockIdx.y * 64, bn = blockIdx.x * 128;
  int tid = threadIdx.x;
  int l = tid & 63;
  int wid = tid >> 6;
  int wr = wid >> 1, wc = wid & 1;
  int rr = l & 15, kc = l >> 4;

  f32x4 acc[2][4];
  #pragma unroll
  for (int i = 0; i < 2; ++i)
    #pragma unroll
    for (int j = 0; j < 4; ++j)
      acc[i][j] = (f32x4){0.f, 0.f, 0.f, 0.f};

  int ar = tid >> 2, ac = tid & 3;
  int gm = bm + ar;
  const uint4 z4 = {0, 0, 0, 0};

  for (int kt = 0; kt < 8; ++kt) {
    int k0 = kt * 32;
    uint4 vh = z4, vl = z4;
    if (gm < M) {
      vh = *(const uint4*)(Ahi + (size_t)gm * 256 + k0 + ac * 8);
      vl = *(const uint4*)(Alo + (size_t)gm * 256 + k0 + ac * 8);
    }
    *(uint4*)&As[0][ar][ac * 8] = vh;
    *(uint4*)&As[1][ar][ac * 8] = vl;
    #pragma unroll
    for (int p = 0; p < 2; ++p) {
      int id = tid + p * 256;
      int nn = id >> 2, cc = id & 3;
      *(uint4*)&Bs[0][nn][cc * 8] = *(const uint4*)(Bth + (size_t)(bn + nn) * 256 + k0 + cc * 8);
      *(uint4*)&Bs[1][nn][cc * 8] = *(const uint4*)(Btl + (size_t)(bn + nn) * 256 + k0 + cc * 8);
    }
    __syncthreads();
    bf16x8 ah[2], alo[2], bh[4], bl[4];
    #pragma unroll
    for (int i = 0; i < 2; ++i) {
      ah[i]  = *(const bf16x8*)&As[0][wr * 32 + i * 16 + rr][kc * 8];
      alo[i] = *(const bf16x8*)&As[1][wr * 32 + i * 16 + rr][kc * 8];
    }
    #pragma unroll
    for (int j = 0; j < 4; ++j) {
      bh[j] = *(const bf16x8*)&Bs[0][wc * 64 + j * 16 + rr][kc * 8];
      bl[j] = *(const bf16x8*)&Bs[1][wc * 64 + j * 16 + rr][kc * 8];
    }
    #pragma unroll
    for (int i = 0; i < 2; ++i)
      #pragma unroll
      for (int j = 0; j < 4; ++j) {
        acc[i][j] = __builtin_amdgcn_mfma_f32_16x16x32_bf16(ah[i],  bh[j], acc[i][j], 0, 0, 0);
        acc[i][j] = __builtin_amdgcn_mfma_f32_16x16x32_bf16(ah[i],  bl[j], acc[i][j], 0, 0, 0);
        acc[i][j] = __builtin_amdgcn_mfma_f32_16x16x32_bf16(alo[i], bh[j], acc[i][j], 0, 0, 0);
      }
    __syncthreads();
  }
  #pragma unroll
  for (int i = 0; i < 2; ++i)
    #pragma unroll
    for (int reg = 0; reg < 4; ++reg) {
      int row = bm + wr * 32 + i * 16 + kc * 4 + reg;
      if (row < M) {
        #pragma unroll
        for (int j = 0; j < 4; ++j) {
          int col = bn + wc * 64 + j * 16 + rr;
          C[(size_t)row * N + col] = acc[i][j][reg];
        }
      }
    }
}

// ---------- per-node attention scalars ----------
template <int H>
__global__ void node_attn(const float* __restrict__ xh, const float* __restrict__ att_src,
                          const float* __restrict__ att_dst, float* __restrict__ asrc,
                          float* __restrict__ adst) {
  int n = blockIdx.x;
  int t = threadIdx.x;  // 0..63
  #pragma unroll
  for (int h = 0; h < H; ++h) {
    float v0 = xh[(size_t)n * (H * 128) + h * 128 + t];
    float v1 = xh[(size_t)n * (H * 128) + h * 128 + 64 + t];
    float ss = v0 * att_src[h * 128 + t] + v1 * att_src[h * 128 + 64 + t];
    float sd = v0 * att_dst[h * 128 + t] + v1 * att_dst[h * 128 + 64 + t];
    #pragma unroll
    for (int off = 32; off > 0; off >>= 1) {
      ss += __shfl_down(ss, off);
      sd += __shfl_down(sd, off);
    }
    if (t == 0) { asrc[n * H + h] = ss; adst[n * H + h] = sd; }
  }
}

// ---------- edge logits (CSR slot order) + segment max ----------
template <int H>
__global__ void edge_logits(const int* __restrict__ ei, const float* __restrict__ ea,
                            const float* __restrict__ lattr, const float* __restrict__ asrc,
                            const float* __restrict__ adst, const float* __restrict__ Ae,
                            const int* __restrict__ epos,
                            float* __restrict__ elog, unsigned* __restrict__ nmax, int aeoff) {
  int e = blockIdx.x * blockDim.x + threadIdx.x;
  if (e >= EP) return;
  int s, d; float e0, e1;
  if (e < N_EDGES) { s = ei[e]; d = ei[N_EDGES + e]; e0 = ea[2 * e]; e1 = ea[2 * e + 1]; }
  else { s = d = e - N_EDGES; e0 = lattr[2 * s]; e1 = lattr[2 * s + 1]; }
  int pos = epos[e];
  #pragma unroll
  for (int h = 0; h < H; ++h) {
    float l = asrc[s * H + h] + adst[d * H + h] + e0 * Ae[aeoff + h] + e1 * Ae[aeoff + H + h];
    l = (l > 0.f) ? l : NEG_SLOPE * l;
    elog[(size_t)pos * H + h] = l;
    atomicMax(&nmax[d * H + h], f2ord(l));
  }
}

// ---------- exp(l - m) in place + segment sum ----------
template <int H>
__global__ void edge_exp(const int* __restrict__ dsts, float* __restrict__ elog,
                         const unsigned* __restrict__ nmax, float* __restrict__ nsum) {
  int i = blockIdx.x * blockDim.x + threadIdx.x;
  if (i >= EP) return;
  int d = dsts[i];
  #pragma unroll
  for (int h = 0; h < H; ++h) {
    float l = elog[(size_t)i * H + h];
    float m = ord2f(nmax[d * H + h]);
    float xv = expf(l - m);
    elog[(size_t)i * H + h] = xv;
    atomicAdd(&nsum[d * H + h], xv);
  }
}

// ---------- CSR aggregation (4-way MLP unroll); SPLIT: emit bf16 hi/lo ----------
template <int H, int ACT, int SPLIT>
__global__ void aggregate(const float* __restrict__ xh, const float* __restrict__ ex,
                          const float* __restrict__ nsum, const int* __restrict__ rowptr,
                          const int* __restrict__ srcs, const float* __restrict__ bias,
                          float* __restrict__ out, unsigned short* __restrict__ ohi,
                          unsigned short* __restrict__ olo) {
  int n = blockIdx.x;
  int t = threadIdx.x;          // 0 .. H*128-1
  int h = t >> 7;
  float inv = 1.0f / (nsum[n * H + h] + 1e-16f);
  int beg = rowptr[n], end = rowptr[n + 1];
  float acc0 = 0.f, acc1 = 0.f, acc2 = 0.f, acc3 = 0.f;
  int j = beg;
  for (; j + 4 <= end; j += 4) {
    int s0 = srcs[j], s1 = srcs[j + 1], s2 = srcs[j + 2], s3 = srcs[j + 3];
    float a0 = ex[(size_t)j * H + h];
    float a1 = ex[(size_t)(j + 1) * H + h];
    float a2 = ex[(size_t)(j + 2) * H + h];
    float a3 = ex[(size_t)(j + 3) * H + h];
    acc0 = fmaf(a0, xh[(size_t)s0 * (H * 128) + t], acc0);
    acc1 = fmaf(a1, xh[(size_t)s1 * (H * 128) + t], acc1);
    acc2 = fmaf(a2, xh[(size_t)s2 * (H * 128) + t], acc2);
    acc3 = fmaf(a3, xh[(size_t)s3 * (H * 128) + t], acc3);
  }
  for (; j < end; ++j) {
    acc0 = fmaf(ex[(size_t)j * H + h], xh[(size_t)srcs[j] * (H * 128) + t], acc0);
  }
  float v = fmaf(inv, (acc0 + acc1) + (acc2 + acc3), bias[t]);
  if (ACT) v = (v > 0.f) ? v : expm1f(v);
  if (SPLIT) {
    unsigned short hh = f2bf(v);
    ohi[(size_t)n * (H * 128) + t] = hh;
    olo[(size_t)n * (H * 128) + t] = f2bf(v - bf2f(hh));
  } else {
    out[(size_t)n * (H * 128) + t] = v;
  }
}

// ---------- launch ----------
extern "C" void kernel_launch(void* const* d_in, const int* in_sizes, int n_in,
                              void* d_out, int out_size, void* d_ws, size_t ws_size,
                              hipStream_t stream) {
  const float* x    = (const float*)d_in[0];
  const int*   ei   = (const int*)d_in[1];
  const float* ea   = (const float*)d_in[2];
  const float* W1   = (const float*)d_in[3];
  const float* as1  = (const float*)d_in[4];
  const float* ad1  = (const float*)d_in[5];
  const float* We1  = (const float*)d_in[6];
  const float* ae1  = (const float*)d_in[7];
  const float* b1   = (const float*)d_in[8];
  const float* W2   = (const float*)d_in[9];
  const float* as2  = (const float*)d_in[10];
  const float* ad2  = (const float*)d_in[11];
  const float* We2  = (const float*)d_in[12];
  const float* ae2  = (const float*)d_in[13];
  const float* b2   = (const float*)d_in[14];
  float* out = (float*)d_out;

  char* w = (char*)d_ws;
  size_t off = 0;
  auto alloc = [&](size_t bytes) -> void* {
    void* p = w + off;
    off = (off + bytes + 255) & ~(size_t)255;
    return p;
  };
  float*          xh    = (float*)alloc((size_t)N_NODES * 256 * 4);   // conv outputs (fp32)
  unsigned short* A1hi  = (unsigned short*)alloc((size_t)N_NODES * 256 * 2);
  unsigned short* A1lo  = (unsigned short*)alloc((size_t)N_NODES * 256 * 2);
  unsigned short* A2hi  = (unsigned short*)alloc((size_t)N_NODES * 256 * 2);
  unsigned short* A2lo  = (unsigned short*)alloc((size_t)N_NODES * 256 * 2);
  unsigned short* B1hi  = (unsigned short*)alloc(256 * 256 * 2);
  unsigned short* B1lo  = (unsigned short*)alloc(256 * 256 * 2);
  unsigned short* B2hi  = (unsigned short*)alloc(128 * 256 * 2);
  unsigned short* B2lo  = (unsigned short*)alloc(128 * 256 * 2);
  float*    elog   = (float*)alloc((size_t)EP * 2 * 4);
  int*      rowptr = (int*)alloc((N_NODES + 1) * 4);
  int*      cursor = (int*)alloc(N_NODES * 4);
  int*      deg    = (int*)alloc(N_NODES * 4);
  int*      srcs   = (int*)alloc((size_t)EP * 4);
  int*      dsts   = (int*)alloc((size_t)EP * 4);
  int*      epos   = (int*)alloc((size_t)EP * 4);
  float*    asrc   = (float*)alloc(N_NODES * 2 * 4);
  float*    adst   = (float*)alloc(N_NODES * 2 * 4);
  unsigned* nmax   = (unsigned*)alloc(N_NODES * 2 * 4);
  float*    nsum   = (float*)alloc(N_NODES * 2 * 4);
  float*    lattr  = (float*)alloc(N_NODES * 2 * 4);
  float*    cnt    = (float*)alloc(N_NODES * 4);
  float*    Ae     = (float*)alloc(16 * 4);

  const unsigned ORDNEGINF = 0x007FFFFFu;
  auto cdiv = [](int a, int b) { return (a + b - 1) / b; };

  // init
  fill_u32<<<cdiv(N_NODES * 2, 256), 256, 0, stream>>>((unsigned*)lattr, 0u, N_NODES * 2);
  fill_u32<<<cdiv(N_NODES, 256), 256, 0, stream>>>((unsigned*)cnt, 0u, N_NODES);
  fill_u32<<<cdiv(N_NODES, 256), 256, 0, stream>>>((unsigned*)deg, 1u, N_NODES); // self loop
  fill_u32<<<cdiv(N_NODES * 2, 256), 256, 0, stream>>>(nmax, ORDNEGINF, N_NODES * 2);
  fill_u32<<<cdiv(N_NODES * 2, 256), 256, 0, stream>>>((unsigned*)nsum, 0u, N_NODES * 2);

  // graph prep + operand prep
  loop_accum<<<cdiv(N_EDGES, 256), 256, 0, stream>>>(ei, ea, lattr, cnt, deg);
  loop_fin<<<cdiv(N_NODES, 256), 256, 0, stream>>>(lattr, cnt);
  scan_deg<<<1, 1024, 0, stream>>>(deg, rowptr, cursor);
  scatter_edges<<<cdiv(EP, 256), 256, 0, stream>>>(ei, cursor, srcs, dsts, epos);
  prep_ae<<<6, 64, 0, stream>>>(We1, ae1, We2, ae2, Ae);
  split_f32<<<cdiv(N_NODES * 256 / 4, 256), 256, 0, stream>>>(x, A1hi, A1lo, N_NODES * 256 / 4);
  bt_split<<<384, 256, 0, stream>>>(W1, W2, B1hi, B1lo, B2hi, B2lo);

  // ---- conv1 (H=2, C=128) ----
  gemm_split<<<dim3(2, cdiv(N_NODES, 64)), 256, 0, stream>>>(A1hi, A1lo, B1hi, B1lo, xh, N_NODES, 256);
  node_attn<2><<<N_NODES, 64, 0, stream>>>(xh, as1, ad1, asrc, adst);
  edge_logits<2><<<cdiv(EP, 256), 256, 0, stream>>>(ei, ea, lattr, asrc, adst, Ae, epos, elog, nmax, 0);
  edge_exp<2><<<cdiv(EP, 256), 256, 0, stream>>>(dsts, elog, nmax, nsum);
  aggregate<2, 1, 1><<<N_NODES, 256, 0, stream>>>(xh, elog, nsum, rowptr, srcs, b1,
                                                  nullptr, A2hi, A2lo);

  // ---- conv2 (H=1, C=128) ----
  fill_u32<<<cdiv(N_NODES, 256), 256, 0, stream>>>(nmax, ORDNEGINF, N_NODES);
  fill_u32<<<cdiv(N_NODES, 256), 256, 0, stream>>>((unsigned*)nsum, 0u, N_NODES);
  gemm_split<<<dim3(1, cdiv(N_NODES, 64)), 256, 0, stream>>>(A2hi, A2lo, B2hi, B2lo, xh, N_NODES, 128);
  node_attn<1><<<N_NODES, 64, 0, stream>>>(xh, as2, ad2, asrc, adst);
  edge_logits<1><<<cdiv(EP, 256), 256, 0, stream>>>(ei, ea, lattr, asrc, adst, Ae, epos, elog, nmax, 4);
  edge_exp<1><<<cdiv(EP, 256), 256, 0, stream>>>(dsts, elog, nmax, nsum);
  aggregate<1, 0, 0><<<N_NODES, 128, 0, stream>>>(xh, elog, nsum, rowptr, srcs, b2,
                                                  out, nullptr, nullptr);
}

// Round 4
// 505.806 us; speedup vs baseline: 2.2456x; 1.7325x over previous
//
#include <hip/hip_runtime.h>
#include <math.h>

#define N_NODES 50000
#define N_EDGES 800000
#define EP (N_EDGES + N_NODES)   // edges incl. self loops
#define NEG_SLOPE 0.2f

typedef __attribute__((ext_vector_type(8))) short bf16x8;
typedef __attribute__((ext_vector_type(4))) float f32x4;

// ---------- helpers ----------
__device__ __forceinline__ unsigned short f2bf(float f) {
  unsigned u = __float_as_uint(f);
  unsigned r = (u + 0x7FFFu + ((u >> 16) & 1u)) >> 16;
  return (unsigned short)r;
}
__device__ __forceinline__ float bf2f(unsigned short b) {
  return __uint_as_float(((unsigned)b) << 16);
}

__global__ void fill_u32(unsigned* p, unsigned v, int n) {
  int i = blockIdx.x * blockDim.x + threadIdx.x;
  if (i < n) p[i] = v;
}

// ---------- degree histogram: 1 atomic per edge (deg pre-filled to 1 = self loop) ----
__global__ void deg_hist(const int* __restrict__ ei, int* __restrict__ deg) {
  int e = blockIdx.x * blockDim.x + threadIdx.x;
  if (e >= N_EDGES) return;
  atomicAdd(&deg[ei[N_EDGES + e]], 1);
}

// ---------- CSR rowptr: chunked single-block exclusive scan ----------
__global__ void scan_deg(const int* __restrict__ deg, int* __restrict__ rowptr,
                         int* __restrict__ cursor) {
  __shared__ int buf[2][1024];
  const int n = N_NODES;
  const int chunk = (n + 1023) / 1024;
  int lo = threadIdx.x * chunk;
  int hi = lo + chunk; if (hi > n) hi = n;
  int s = 0;
  for (int i = lo; i < hi; ++i) s += deg[i];
  buf[0][threadIdx.x] = s;
  __syncthreads();
  int cur = 0;
  for (int off = 1; off < 1024; off <<= 1) {
    int t = buf[cur][threadIdx.x];
    if ((int)threadIdx.x >= off) t += buf[cur][threadIdx.x - off];
    buf[cur ^ 1][threadIdx.x] = t;
    cur ^= 1;
    __syncthreads();
  }
  int excl = buf[cur][threadIdx.x] - s;
  int run = excl;
  for (int i = lo; i < hi; ++i) {
    rowptr[i] = run; cursor[i] = run;
    run += deg[i];
  }
  if (threadIdx.x == 1023) rowptr[n] = buf[cur][1023];
}

// ---------- scatter edges into CSR slots; ea stored in slot order ----------
__global__ void scatter_ea(const int* __restrict__ ei, const float* __restrict__ ea,
                           int* __restrict__ cursor, int* __restrict__ srcs,
                           float2* __restrict__ ea_csr, int* __restrict__ loopslot) {
  int e = blockIdx.x * blockDim.x + threadIdx.x;
  if (e >= EP) return;
  int s, d; float2 v;
  if (e < N_EDGES) { s = ei[e]; d = ei[N_EDGES + e]; v.x = ea[2 * e]; v.y = ea[2 * e + 1]; }
  else { s = d = e - N_EDGES; v.x = 0.f; v.y = 0.f; }   // self-loop attr filled later
  int pos = atomicAdd(&cursor[d], 1);
  srcs[pos] = s;
  ea_csr[pos] = v;
  if (e >= N_EDGES) loopslot[d] = pos;
}

// ---------- self-loop attr = mean of incoming ea (sequential segment sum) ----------
__global__ void lattr_fin(const int* __restrict__ rowptr, const int* __restrict__ loopslot,
                          float2* __restrict__ ea_csr) {
  int n = blockIdx.x * blockDim.x + threadIdx.x;
  if (n >= N_NODES) return;
  int beg = rowptr[n], end = rowptr[n + 1];
  float s0 = 0.f, s1 = 0.f;
  for (int j = beg; j < end; ++j) {       // loop slot holds (0,0): contributes nothing
    float2 e = ea_csr[j];
    s0 += e.x; s1 += e.y;
  }
  float c = fmaxf((float)(end - beg - 1), 1.0f);
  float2 m; m.x = s0 / c; m.y = s1 / c;
  ea_csr[loopslot[n]] = m;
}

// ---------- Ae[d][h] = sum_c We[d, h*128+c] * att_e[h,c] ----------
__global__ void prep_ae(const float* __restrict__ We1, const float* __restrict__ ae1,
                        const float* __restrict__ We2, const float* __restrict__ ae2,
                        float* __restrict__ Ae) {
  int b = blockIdx.x;
  int t = threadIdx.x;
  float s = 0.f;
  if (b < 4) {
    int d = b >> 1, h = b & 1;
    for (int c = t; c < 128; c += 64)
      s += We1[d * 256 + h * 128 + c] * ae1[h * 128 + c];
  } else {
    int d = b - 4;
    for (int c = t; c < 128; c += 64)
      s += We2[d * 128 + c] * ae2[c];
  }
  for (int off = 32; off > 0; off >>= 1) s += __shfl_down(s, off);
  if (t == 0) Ae[b] = s;   // [d0h0, d0h1, d1h0, d1h1, d0(conv2), d1(conv2)]
}

// ---------- fp32 -> bf16 hi/lo split (elementwise, float4 vectorized) ----------
__global__ void split_f32(const float* __restrict__ in, unsigned short* __restrict__ hi,
                          unsigned short* __restrict__ lo, int n4) {
  int i = blockIdx.x * blockDim.x + threadIdx.x;
  if (i >= n4) return;
  float4 v = ((const float4*)in)[i];
  ushort4 h, l;
  h.x = f2bf(v.x); l.x = f2bf(v.x - bf2f(h.x));
  h.y = f2bf(v.y); l.y = f2bf(v.y - bf2f(h.y));
  h.z = f2bf(v.z); l.z = f2bf(v.z - bf2f(h.z));
  h.w = f2bf(v.w); l.w = f2bf(v.w - bf2f(h.w));
  ((ushort4*)hi)[i] = h;
  ((ushort4*)lo)[i] = l;
}

// ---------- W -> W^T hi/lo split (tiny, cached) ----------
__global__ void bt_split(const float* __restrict__ W1, const float* __restrict__ W2,
                         unsigned short* __restrict__ b1h, unsigned short* __restrict__ b1l,
                         unsigned short* __restrict__ b2h, unsigned short* __restrict__ b2l) {
  int n = blockIdx.x;
  int k = threadIdx.x;   // 256
  float v; unsigned short* ph; unsigned short* pl; int idx;
  if (n < 256) { v = W1[k * 256 + n];       ph = b1h; pl = b1l; idx = n * 256 + k; }
  else         { v = W2[k * 128 + (n - 256)]; ph = b2h; pl = b2l; idx = (n - 256) * 256 + k; }
  unsigned short h = f2bf(v);
  ph[idx] = h;
  pl[idx] = f2bf(v - bf2f(h));
}

// ---------- split-bf16 MFMA GEMM: C[M,N] = A[M,256] @ B[256,N] (fp32-accurate) ----
__global__ __launch_bounds__(256) void gemm_split(
    const unsigned short* __restrict__ Ahi, const unsigned short* __restrict__ Alo,
    const unsigned short* __restrict__ Bth, const unsigned short* __restrict__ Btl,
    float* __restrict__ C, int M, int N) {
  __shared__ __attribute__((aligned(16))) unsigned short As[2][64][40];
  __shared__ __attribute__((aligned(16))) unsigned short Bs[2][128][40];
  int bm = blockIdx.y * 64, bn = blockIdx.x * 128;
  int tid = threadIdx.x;
  int l = tid & 63;
  int wid = tid >> 6;
  int wr = wid >> 1, wc = wid & 1;
  int rr = l & 15, kc = l >> 4;

  f32x4 acc[2][4];
  #pragma unroll
  for (int i = 0; i < 2; ++i)
    #pragma unroll
    for (int j = 0; j < 4; ++j)
      acc[i][j] = (f32x4){0.f, 0.f, 0.f, 0.f};

  int ar = tid >> 2, ac = tid & 3;
  int gm = bm + ar;
  const uint4 z4 = {0, 0, 0, 0};

  for (int kt = 0; kt < 8; ++kt) {
    int k0 = kt * 32;
    uint4 vh = z4, vl = z4;
    if (gm < M) {
      vh = *(const uint4*)(Ahi + (size_t)gm * 256 + k0 + ac * 8);
      vl = *(const uint4*)(Alo + (size_t)gm * 256 + k0 + ac * 8);
    }
    *(uint4*)&As[0][ar][ac * 8] = vh;
    *(uint4*)&As[1][ar][ac * 8] = vl;
    #pragma unroll
    for (int p = 0; p < 2; ++p) {
      int id = tid + p * 256;
      int nn = id >> 2, cc = id & 3;
      *(uint4*)&Bs[0][nn][cc * 8] = *(const uint4*)(Bth + (size_t)(bn + nn) * 256 + k0 + cc * 8);
      *(uint4*)&Bs[1][nn][cc * 8] = *(const uint4*)(Btl + (size_t)(bn + nn) * 256 + k0 + cc * 8);
    }
    __syncthreads();
    bf16x8 ah[2], alo[2], bh[4], bl[4];
    #pragma unroll
    for (int i = 0; i < 2; ++i) {
      ah[i]  = *(const bf16x8*)&As[0][wr * 32 + i * 16 + rr][kc * 8];
      alo[i] = *(const bf16x8*)&As[1][wr * 32 + i * 16 + rr][kc * 8];
    }
    #pragma unroll
    for (int j = 0; j < 4; ++j) {
      bh[j] = *(const bf16x8*)&Bs[0][wc * 64 + j * 16 + rr][kc * 8];
      bl[j] = *(const bf16x8*)&Bs[1][wc * 64 + j * 16 + rr][kc * 8];
    }
    #pragma unroll
    for (int i = 0; i < 2; ++i)
      #pragma unroll
      for (int j = 0; j < 4; ++j) {
        acc[i][j] = __builtin_amdgcn_mfma_f32_16x16x32_bf16(ah[i],  bh[j], acc[i][j], 0, 0, 0);
        acc[i][j] = __builtin_amdgcn_mfma_f32_16x16x32_bf16(ah[i],  bl[j], acc[i][j], 0, 0, 0);
        acc[i][j] = __builtin_amdgcn_mfma_f32_16x16x32_bf16(alo[i], bh[j], acc[i][j], 0, 0, 0);
      }
    __syncthreads();
  }
  #pragma unroll
  for (int i = 0; i < 2; ++i)
    #pragma unroll
    for (int reg = 0; reg < 4; ++reg) {
      int row = bm + wr * 32 + i * 16 + kc * 4 + reg;
      if (row < M) {
        #pragma unroll
        for (int j = 0; j < 4; ++j) {
          int col = bn + wc * 64 + j * 16 + rr;
          C[(size_t)row * N + col] = acc[i][j][reg];
        }
      }
    }
}

// ---------- per-node attention scalars ----------
template <int H>
__global__ void node_attn(const float* __restrict__ xh, const float* __restrict__ att_src,
                          const float* __restrict__ att_dst, float* __restrict__ asrc,
                          float* __restrict__ adst) {
  int n = blockIdx.x;
  int t = threadIdx.x;  // 0..63
  #pragma unroll
  for (int h = 0; h < H; ++h) {
    float v0 = xh[(size_t)n * (H * 128) + h * 128 + t];
    float v1 = xh[(size_t)n * (H * 128) + h * 128 + 64 + t];
    float ss = v0 * att_src[h * 128 + t] + v1 * att_src[h * 128 + 64 + t];
    float sd = v0 * att_dst[h * 128 + t] + v1 * att_dst[h * 128 + 64 + t];
    #pragma unroll
    for (int off = 32; off > 0; off >>= 1) {
      ss += __shfl_down(ss, off);
      sd += __shfl_down(sd, off);
    }
    if (t == 0) { asrc[n * H + h] = ss; adst[n * H + h] = sd; }
  }
}

// ---------- fused: logits + exp + softmax-denominator + weighted aggregation ------
// One block per node. Phase A: segment logits -> exp into LDS (no max subtraction:
// logits bounded ~|6| for this data; normalization makes it math-identical).
// Phase B: 4-way unrolled weighted gather of xh rows. Chunked for arbitrary degree.
template <int H, int ACT, int SPLIT>
__global__ __launch_bounds__(H * 128)
void aggregate_fused(const float* __restrict__ xh, const float* __restrict__ asrc,
                     const float* __restrict__ adst, const float2* __restrict__ ea_csr,
                     const int* __restrict__ rowptr, const int* __restrict__ srcs,
                     const float* __restrict__ Ae, int aeoff,
                     const float* __restrict__ bias, float* __restrict__ out,
                     unsigned short* __restrict__ ohi, unsigned short* __restrict__ olo) {
  constexpr int D = H * 128;
  constexpr int NW = D / 64;
  __shared__ float exl[256][H];
  __shared__ int sl[256];
  __shared__ float wred[NW * H];
  __shared__ float totsum[H];
  int n = blockIdx.x;
  int t = threadIdx.x;
  int beg = rowptr[n], end = rowptr[n + 1];
  int hA = t & (H - 1);                 // phase-A head (fixed per thread)
  float adnA = adst[n * H + hA];
  float Ae0 = Ae[aeoff + hA], Ae1 = Ae[aeoff + H + hA];
  int hB = t >> 7;                      // phase-B head (column ownership)
  float lsum = 0.f;
  float a0 = 0.f, a1 = 0.f, a2 = 0.f, a3 = 0.f;

  for (int cbeg = beg; cbeg < end; cbeg += 256) {
    int cnt = min(256, end - cbeg);
    for (int idx = t; idx < cnt * H; idx += D) {
      int j0 = idx / H;
      int jj = cbeg + j0;
      int s = srcs[jj];
      float2 e = ea_csr[jj];
      float lg = asrc[s * H + hA] + adnA + e.x * Ae0 + e.y * Ae1;
      lg = (lg > 0.f) ? lg : NEG_SLOPE * lg;
      float ex = expf(lg);
      exl[j0][hA] = ex;
      if (hA == 0) sl[j0] = s;
      lsum += ex;
    }
    __syncthreads();
    int j = 0;
    for (; j + 4 <= cnt; j += 4) {
      float e0 = exl[j][hB], e1 = exl[j + 1][hB], e2 = exl[j + 2][hB], e3 = exl[j + 3][hB];
      int s0 = sl[j], s1 = sl[j + 1], s2 = sl[j + 2], s3 = sl[j + 3];
      a0 = fmaf(e0, xh[(size_t)s0 * D + t], a0);
      a1 = fmaf(e1, xh[(size_t)s1 * D + t], a1);
      a2 = fmaf(e2, xh[(size_t)s2 * D + t], a2);
      a3 = fmaf(e3, xh[(size_t)s3 * D + t], a3);
    }
    for (; j < cnt; ++j)
      a0 = fmaf(exl[j][hB], xh[(size_t)sl[j] * D + t], a0);
    __syncthreads();
  }

  // block-reduce lsum per head class (parity classes of width H within each wave)
  #pragma unroll
  for (int off = H; off < 64; off <<= 1) lsum += __shfl_xor(lsum, off);
  int lane = t & 63, wid = t >> 6;
  if (lane < H) wred[wid * H + lane] = lsum;
  __syncthreads();
  if (t < H) {
    float tot = 0.f;
    for (int wv = 0; wv < NW; ++wv) tot += wred[wv * H + t];
    totsum[t] = tot;
  }
  __syncthreads();
  float inv = 1.0f / (totsum[hB] + 1e-16f);
  float v = fmaf(inv, (a0 + a1) + (a2 + a3), bias[t]);
  if (ACT) v = (v > 0.f) ? v : expm1f(v);
  if (SPLIT) {
    unsigned short hh = f2bf(v);
    ohi[(size_t)n * D + t] = hh;
    olo[(size_t)n * D + t] = f2bf(v - bf2f(hh));
  } else {
    out[(size_t)n * D + t] = v;
  }
}

// ---------- launch ----------
extern "C" void kernel_launch(void* const* d_in, const int* in_sizes, int n_in,
                              void* d_out, int out_size, void* d_ws, size_t ws_size,
                              hipStream_t stream) {
  const float* x    = (const float*)d_in[0];
  const int*   ei   = (const int*)d_in[1];
  const float* ea   = (const float*)d_in[2];
  const float* W1   = (const float*)d_in[3];
  const float* as1  = (const float*)d_in[4];
  const float* ad1  = (const float*)d_in[5];
  const float* We1  = (const float*)d_in[6];
  const float* ae1  = (const float*)d_in[7];
  const float* b1   = (const float*)d_in[8];
  const float* W2   = (const float*)d_in[9];
  const float* as2  = (const float*)d_in[10];
  const float* ad2  = (const float*)d_in[11];
  const float* We2  = (const float*)d_in[12];
  const float* ae2  = (const float*)d_in[13];
  const float* b2   = (const float*)d_in[14];
  float* out = (float*)d_out;

  char* w = (char*)d_ws;
  size_t off = 0;
  auto alloc = [&](size_t bytes) -> void* {
    void* p = w + off;
    off = (off + bytes + 255) & ~(size_t)255;
    return p;
  };
  float*          xh    = (float*)alloc((size_t)N_NODES * 256 * 4);
  unsigned short* A1hi  = (unsigned short*)alloc((size_t)N_NODES * 256 * 2);
  unsigned short* A1lo  = (unsigned short*)alloc((size_t)N_NODES * 256 * 2);
  unsigned short* A2hi  = (unsigned short*)alloc((size_t)N_NODES * 256 * 2);
  unsigned short* A2lo  = (unsigned short*)alloc((size_t)N_NODES * 256 * 2);
  unsigned short* B1hi  = (unsigned short*)alloc(256 * 256 * 2);
  unsigned short* B1lo  = (unsigned short*)alloc(256 * 256 * 2);
  unsigned short* B2hi  = (unsigned short*)alloc(128 * 256 * 2);
  unsigned short* B2lo  = (unsigned short*)alloc(128 * 256 * 2);
  int*      rowptr   = (int*)alloc((N_NODES + 1) * 4);
  int*      cursor   = (int*)alloc(N_NODES * 4);
  int*      deg      = (int*)alloc(N_NODES * 4);
  int*      loopslot = (int*)alloc(N_NODES * 4);
  int*      srcs     = (int*)alloc((size_t)EP * 4);
  float2*   ea_csr   = (float2*)alloc((size_t)EP * 8);
  float*    asrc     = (float*)alloc(N_NODES * 2 * 4);
  float*    adst     = (float*)alloc(N_NODES * 2 * 4);
  float*    Ae       = (float*)alloc(16 * 4);

  auto cdiv = [](int a, int b) { return (a + b - 1) / b; };

  // graph prep (atomic-minimal): deg histogram -> scan -> scatter -> self-loop attr
  fill_u32<<<cdiv(N_NODES, 256), 256, 0, stream>>>((unsigned*)deg, 1u, N_NODES);
  deg_hist<<<cdiv(N_EDGES, 256), 256, 0, stream>>>(ei, deg);
  scan_deg<<<1, 1024, 0, stream>>>(deg, rowptr, cursor);
  scatter_ea<<<cdiv(EP, 256), 256, 0, stream>>>(ei, ea, cursor, srcs, ea_csr, loopslot);
  lattr_fin<<<cdiv(N_NODES, 256), 256, 0, stream>>>(rowptr, loopslot, ea_csr);

  // operand prep
  prep_ae<<<6, 64, 0, stream>>>(We1, ae1, We2, ae2, Ae);
  split_f32<<<cdiv(N_NODES * 256 / 4, 256), 256, 0, stream>>>(x, A1hi, A1lo, N_NODES * 256 / 4);
  bt_split<<<384, 256, 0, stream>>>(W1, W2, B1hi, B1lo, B2hi, B2lo);

  // ---- conv1 (H=2, C=128) ----
  gemm_split<<<dim3(2, cdiv(N_NODES, 64)), 256, 0, stream>>>(A1hi, A1lo, B1hi, B1lo, xh, N_NODES, 256);
  node_attn<2><<<N_NODES, 64, 0, stream>>>(xh, as1, ad1, asrc, adst);
  aggregate_fused<2, 1, 1><<<N_NODES, 256, 0, stream>>>(xh, asrc, adst, ea_csr, rowptr, srcs,
                                                        Ae, 0, b1, nullptr, A2hi, A2lo);

  // ---- conv2 (H=1, C=128) ----
  gemm_split<<<dim3(1, cdiv(N_NODES, 64)), 256, 0, stream>>>(A2hi, A2lo, B2hi, B2lo, xh, N_NODES, 128);
  node_attn<1><<<N_NODES, 64, 0, stream>>>(xh, as2, ad2, asrc, adst);
  aggregate_fused<1, 0, 0><<<N_NODES, 128, 0, stream>>>(xh, asrc, adst, ea_csr, rowptr, srcs,
                                                        Ae, 4, b2, out, nullptr, nullptr);
}

// Round 5
// 466.595 us; speedup vs baseline: 2.4343x; 1.0840x over previous
//
#include <hip/hip_runtime.h>
#include <math.h>

#define N_NODES 50000
#define N_EDGES 800000
#define EP (N_EDGES + N_NODES)   // edges incl. self loops
#define NEG_SLOPE 0.2f

typedef __attribute__((ext_vector_type(8))) short bf16x8;
typedef __attribute__((ext_vector_type(4))) float f32x4;

// ---------- helpers ----------
__device__ __forceinline__ unsigned short f2bf(float f) {
  unsigned u = __float_as_uint(f);
  unsigned r = (u + 0x7FFFu + ((u >> 16) & 1u)) >> 16;
  return (unsigned short)r;
}
__device__ __forceinline__ float bf2f(unsigned short b) {
  return __uint_as_float(((unsigned)b) << 16);
}

__global__ void fill_u32(unsigned* p, unsigned v, int n) {
  int i = blockIdx.x * blockDim.x + threadIdx.x;
  if (i < n) p[i] = v;
}

// ---------- degree histogram: 1 atomic per edge (deg pre-filled to 1 = self loop) ----
__global__ void deg_hist(const int* __restrict__ ei, int* __restrict__ deg) {
  int e = blockIdx.x * blockDim.x + threadIdx.x;
  if (e >= N_EDGES) return;
  atomicAdd(&deg[ei[N_EDGES + e]], 1);
}

// ---------- CSR rowptr: chunked single-block exclusive scan ----------
__global__ void scan_deg(const int* __restrict__ deg, int* __restrict__ rowptr,
                         int* __restrict__ cursor) {
  __shared__ int buf[2][1024];
  const int n = N_NODES;
  const int chunk = (n + 1023) / 1024;
  int lo = threadIdx.x * chunk;
  int hi = lo + chunk; if (hi > n) hi = n;
  int s = 0;
  for (int i = lo; i < hi; ++i) s += deg[i];
  buf[0][threadIdx.x] = s;
  __syncthreads();
  int cur = 0;
  for (int off = 1; off < 1024; off <<= 1) {
    int t = buf[cur][threadIdx.x];
    if ((int)threadIdx.x >= off) t += buf[cur][threadIdx.x - off];
    buf[cur ^ 1][threadIdx.x] = t;
    cur ^= 1;
    __syncthreads();
  }
  int excl = buf[cur][threadIdx.x] - s;
  int run = excl;
  for (int i = lo; i < hi; ++i) {
    rowptr[i] = run; cursor[i] = run;
    run += deg[i];
  }
  if (threadIdx.x == 1023) rowptr[n] = buf[cur][1023];
}

// ---------- scatter edges into CSR slots; ea stored in slot order ----------
__global__ void scatter_ea(const int* __restrict__ ei, const float* __restrict__ ea,
                           int* __restrict__ cursor, int* __restrict__ srcs,
                           float2* __restrict__ ea_csr, int* __restrict__ loopslot) {
  int e = blockIdx.x * blockDim.x + threadIdx.x;
  if (e >= EP) return;
  int s, d; float2 v;
  if (e < N_EDGES) { s = ei[e]; d = ei[N_EDGES + e]; v.x = ea[2 * e]; v.y = ea[2 * e + 1]; }
  else { s = d = e - N_EDGES; v.x = 0.f; v.y = 0.f; }   // self-loop attr filled later
  int pos = atomicAdd(&cursor[d], 1);
  srcs[pos] = s;
  ea_csr[pos] = v;
  if (e >= N_EDGES) loopslot[d] = pos;
}

// ---------- self-loop attr = mean of incoming ea (sequential segment sum) ----------
__global__ void lattr_fin(const int* __restrict__ rowptr, const int* __restrict__ loopslot,
                          float2* __restrict__ ea_csr) {
  int n = blockIdx.x * blockDim.x + threadIdx.x;
  if (n >= N_NODES) return;
  int beg = rowptr[n], end = rowptr[n + 1];
  float s0 = 0.f, s1 = 0.f;
  for (int j = beg; j < end; ++j) {       // loop slot holds (0,0): contributes nothing
    float2 e = ea_csr[j];
    s0 += e.x; s1 += e.y;
  }
  float c = fmaxf((float)(end - beg - 1), 1.0f);
  float2 m; m.x = s0 / c; m.y = s1 / c;
  ea_csr[loopslot[n]] = m;
}

// ---------- Ae[d][h] = sum_c We[d, h*128+c] * att_e[h,c] ----------
__global__ void prep_ae(const float* __restrict__ We1, const float* __restrict__ ae1,
                        const float* __restrict__ We2, const float* __restrict__ ae2,
                        float* __restrict__ Ae) {
  int b = blockIdx.x;
  int t = threadIdx.x;
  float s = 0.f;
  if (b < 4) {
    int d = b >> 1, h = b & 1;
    for (int c = t; c < 128; c += 64)
      s += We1[d * 256 + h * 128 + c] * ae1[h * 128 + c];
  } else {
    int d = b - 4;
    for (int c = t; c < 128; c += 64)
      s += We2[d * 128 + c] * ae2[c];
  }
  for (int off = 32; off > 0; off >>= 1) s += __shfl_down(s, off);
  if (t == 0) Ae[b] = s;   // [d0h0, d0h1, d1h0, d1h1, d0(conv2), d1(conv2)]
}

// ---------- W -> W^T hi/lo split (tiny, cached) ----------
__global__ void bt_split(const float* __restrict__ W1, const float* __restrict__ W2,
                         unsigned short* __restrict__ b1h, unsigned short* __restrict__ b1l,
                         unsigned short* __restrict__ b2h, unsigned short* __restrict__ b2l) {
  int n = blockIdx.x;
  int k = threadIdx.x;   // 256
  float v; unsigned short* ph; unsigned short* pl; int idx;
  if (n < 256) { v = W1[k * 256 + n];       ph = b1h; pl = b1l; idx = n * 256 + k; }
  else         { v = W2[k * 128 + (n - 256)]; ph = b2h; pl = b2l; idx = (n - 256) * 256 + k; }
  unsigned short h = f2bf(v);
  ph[idx] = h;
  pl[idx] = f2bf(v - bf2f(h));
}

// ---------- split-bf16 MFMA GEMM (fp32-accurate): C_bf16[M,N] = A_f32[M,256] @ B ----
// A read fp32, split hi/lo in-register into LDS. B given as B^T hi/lo bf16 [N][256].
// Block tile 64x128, BK=32, 4 waves (2x2), wave tile 32x64 (2x4 16x16 frags).
__global__ __launch_bounds__(256) void gemm_split(
    const float* __restrict__ A,
    const unsigned short* __restrict__ Bth, const unsigned short* __restrict__ Btl,
    unsigned short* __restrict__ C, int M, int N) {
  __shared__ __attribute__((aligned(16))) unsigned short As[2][64][40];
  __shared__ __attribute__((aligned(16))) unsigned short Bs[2][128][40];
  int bm = blockIdx.y * 64, bn = blockIdx.x * 128;
  int tid = threadIdx.x;
  int l = tid & 63;
  int wid = tid >> 6;
  int wr = wid >> 1, wc = wid & 1;
  int rr = l & 15, kc = l >> 4;

  f32x4 acc[2][4];
  #pragma unroll
  for (int i = 0; i < 2; ++i)
    #pragma unroll
    for (int j = 0; j < 4; ++j)
      acc[i][j] = (f32x4){0.f, 0.f, 0.f, 0.f};

  int ar = tid >> 2, ac = tid & 3;
  int gm = bm + ar;

  for (int kt = 0; kt < 8; ++kt) {
    int k0 = kt * 32;
    float4 f0 = {0.f, 0.f, 0.f, 0.f}, f1 = f0;
    if (gm < M) {
      f0 = *(const float4*)(A + (size_t)gm * 256 + k0 + ac * 8);
      f1 = *(const float4*)(A + (size_t)gm * 256 + k0 + ac * 8 + 4);
    }
    float f[8] = {f0.x, f0.y, f0.z, f0.w, f1.x, f1.y, f1.z, f1.w};
    unsigned hw[4], lw[4];
    #pragma unroll
    for (int q = 0; q < 4; ++q) {
      unsigned short ha = f2bf(f[2 * q]),  hb = f2bf(f[2 * q + 1]);
      unsigned short la = f2bf(f[2 * q] - bf2f(ha)), lb = f2bf(f[2 * q + 1] - bf2f(hb));
      hw[q] = (unsigned)ha | ((unsigned)hb << 16);
      lw[q] = (unsigned)la | ((unsigned)lb << 16);
    }
    *(uint4*)&As[0][ar][ac * 8] = make_uint4(hw[0], hw[1], hw[2], hw[3]);
    *(uint4*)&As[1][ar][ac * 8] = make_uint4(lw[0], lw[1], lw[2], lw[3]);
    #pragma unroll
    for (int p = 0; p < 2; ++p) {
      int id = tid + p * 256;
      int nn = id >> 2, cc = id & 3;
      *(uint4*)&Bs[0][nn][cc * 8] = *(const uint4*)(Bth + (size_t)(bn + nn) * 256 + k0 + cc * 8);
      *(uint4*)&Bs[1][nn][cc * 8] = *(const uint4*)(Btl + (size_t)(bn + nn) * 256 + k0 + cc * 8);
    }
    __syncthreads();
    bf16x8 ah[2], alo[2], bh[4], bl[4];
    #pragma unroll
    for (int i = 0; i < 2; ++i) {
      ah[i]  = *(const bf16x8*)&As[0][wr * 32 + i * 16 + rr][kc * 8];
      alo[i] = *(const bf16x8*)&As[1][wr * 32 + i * 16 + rr][kc * 8];
    }
    #pragma unroll
    for (int j = 0; j < 4; ++j) {
      bh[j] = *(const bf16x8*)&Bs[0][wc * 64 + j * 16 + rr][kc * 8];
      bl[j] = *(const bf16x8*)&Bs[1][wc * 64 + j * 16 + rr][kc * 8];
    }
    #pragma unroll
    for (int i = 0; i < 2; ++i)
      #pragma unroll
      for (int j = 0; j < 4; ++j) {
        acc[i][j] = __builtin_amdgcn_mfma_f32_16x16x32_bf16(ah[i],  bh[j], acc[i][j], 0, 0, 0);
        acc[i][j] = __builtin_amdgcn_mfma_f32_16x16x32_bf16(ah[i],  bl[j], acc[i][j], 0, 0, 0);
        acc[i][j] = __builtin_amdgcn_mfma_f32_16x16x32_bf16(alo[i], bh[j], acc[i][j], 0, 0, 0);
      }
    __syncthreads();
  }
  #pragma unroll
  for (int i = 0; i < 2; ++i)
    #pragma unroll
    for (int reg = 0; reg < 4; ++reg) {
      int row = bm + wr * 32 + i * 16 + kc * 4 + reg;
      if (row < M) {
        #pragma unroll
        for (int j = 0; j < 4; ++j) {
          int col = bn + wc * 64 + j * 16 + rr;
          C[(size_t)row * N + col] = f2bf(acc[i][j][reg]);
        }
      }
    }
}

// ---------- per-node attention scalars (bf16 xh) ----------
template <int H>
__global__ void node_attn(const unsigned short* __restrict__ xh,
                          const float* __restrict__ att_src,
                          const float* __restrict__ att_dst, float* __restrict__ asrc,
                          float* __restrict__ adst) {
  int n = blockIdx.x;
  int t = threadIdx.x;  // 0..63
  #pragma unroll
  for (int h = 0; h < H; ++h) {
    float v0 = bf2f(xh[(size_t)n * (H * 128) + h * 128 + t]);
    float v1 = bf2f(xh[(size_t)n * (H * 128) + h * 128 + 64 + t]);
    float ss = v0 * att_src[h * 128 + t] + v1 * att_src[h * 128 + 64 + t];
    float sd = v0 * att_dst[h * 128 + t] + v1 * att_dst[h * 128 + 64 + t];
    #pragma unroll
    for (int off = 32; off > 0; off >>= 1) {
      ss += __shfl_down(ss, off);
      sd += __shfl_down(sd, off);
    }
    if (t == 0) { asrc[n * H + h] = ss; adst[n * H + h] = sd; }
  }
}

// ---------- fused: logits + exp + softmax-denominator + weighted aggregation ------
// One block per node; xh messages in bf16 (halved gather bytes), fp32 accumulate.
template <int H, int ACT>
__global__ __launch_bounds__(H * 128)
void aggregate_fused(const unsigned short* __restrict__ xh, const float* __restrict__ asrc,
                     const float* __restrict__ adst, const float2* __restrict__ ea_csr,
                     const int* __restrict__ rowptr, const int* __restrict__ srcs,
                     const float* __restrict__ Ae, int aeoff,
                     const float* __restrict__ bias, float* __restrict__ out) {
  constexpr int D = H * 128;
  constexpr int NW = D / 64;
  __shared__ float exl[256][H];
  __shared__ int sl[256];
  __shared__ float wred[NW * H];
  __shared__ float totsum[H];
  int n = blockIdx.x;
  int t = threadIdx.x;
  int beg = rowptr[n], end = rowptr[n + 1];
  int hA = t & (H - 1);                 // phase-A head (fixed per thread)
  float adnA = adst[n * H + hA];
  float Ae0 = Ae[aeoff + hA], Ae1 = Ae[aeoff + H + hA];
  int hB = t >> 7;                      // phase-B head (column ownership)
  float lsum = 0.f;
  float a0 = 0.f, a1 = 0.f, a2 = 0.f, a3 = 0.f;

  for (int cbeg = beg; cbeg < end; cbeg += 256) {
    int cnt = min(256, end - cbeg);
    for (int idx = t; idx < cnt * H; idx += D) {
      int j0 = idx / H;
      int jj = cbeg + j0;
      int s = srcs[jj];
      float2 e = ea_csr[jj];
      float lg = asrc[s * H + hA] + adnA + e.x * Ae0 + e.y * Ae1;
      lg = (lg > 0.f) ? lg : NEG_SLOPE * lg;
      float ex = expf(lg);
      exl[j0][hA] = ex;
      if (hA == 0) sl[j0] = s;
      lsum += ex;
    }
    __syncthreads();
    int j = 0;
    for (; j + 4 <= cnt; j += 4) {
      float e0 = exl[j][hB], e1 = exl[j + 1][hB], e2 = exl[j + 2][hB], e3 = exl[j + 3][hB];
      int s0 = sl[j], s1 = sl[j + 1], s2 = sl[j + 2], s3 = sl[j + 3];
      a0 = fmaf(e0, bf2f(xh[(size_t)s0 * D + t]), a0);
      a1 = fmaf(e1, bf2f(xh[(size_t)s1 * D + t]), a1);
      a2 = fmaf(e2, bf2f(xh[(size_t)s2 * D + t]), a2);
      a3 = fmaf(e3, bf2f(xh[(size_t)s3 * D + t]), a3);
    }
    for (; j < cnt; ++j)
      a0 = fmaf(exl[j][hB], bf2f(xh[(size_t)sl[j] * D + t]), a0);
    __syncthreads();
  }

  // block-reduce lsum per head class (parity classes of width H within each wave)
  #pragma unroll
  for (int off = H; off < 64; off <<= 1) lsum += __shfl_xor(lsum, off);
  int lane = t & 63, wid = t >> 6;
  if (lane < H) wred[wid * H + lane] = lsum;
  __syncthreads();
  if (t < H) {
    float tot = 0.f;
    for (int wv = 0; wv < NW; ++wv) tot += wred[wv * H + t];
    totsum[t] = tot;
  }
  __syncthreads();
  float inv = 1.0f / (totsum[hB] + 1e-16f);
  float v = fmaf(inv, (a0 + a1) + (a2 + a3), bias[t]);
  if (ACT) v = (v > 0.f) ? v : expm1f(v);
  out[(size_t)n * D + t] = v;
}

// ---------- launch ----------
extern "C" void kernel_launch(void* const* d_in, const int* in_sizes, int n_in,
                              void* d_out, int out_size, void* d_ws, size_t ws_size,
                              hipStream_t stream) {
  const float* x    = (const float*)d_in[0];
  const int*   ei   = (const int*)d_in[1];
  const float* ea   = (const float*)d_in[2];
  const float* W1   = (const float*)d_in[3];
  const float* as1  = (const float*)d_in[4];
  const float* ad1  = (const float*)d_in[5];
  const float* We1  = (const float*)d_in[6];
  const float* ae1  = (const float*)d_in[7];
  const float* b1   = (const float*)d_in[8];
  const float* W2   = (const float*)d_in[9];
  const float* as2  = (const float*)d_in[10];
  const float* ad2  = (const float*)d_in[11];
  const float* We2  = (const float*)d_in[12];
  const float* ae2  = (const float*)d_in[13];
  const float* b2   = (const float*)d_in[14];
  float* out = (float*)d_out;

  char* w = (char*)d_ws;
  size_t off = 0;
  auto alloc = [&](size_t bytes) -> void* {
    void* p = w + off;
    off = (off + bytes + 255) & ~(size_t)255;
    return p;
  };
  unsigned short* xhb   = (unsigned short*)alloc((size_t)N_NODES * 256 * 2); // bf16 conv outputs
  float*          hbuf  = (float*)alloc((size_t)N_NODES * 256 * 4);          // conv1 aggregate (fp32)
  unsigned short* B1hi  = (unsigned short*)alloc(256 * 256 * 2);
  unsigned short* B1lo  = (unsigned short*)alloc(256 * 256 * 2);
  unsigned short* B2hi  = (unsigned short*)alloc(128 * 256 * 2);
  unsigned short* B2lo  = (unsigned short*)alloc(128 * 256 * 2);
  int*      rowptr   = (int*)alloc((N_NODES + 1) * 4);
  int*      cursor   = (int*)alloc(N_NODES * 4);
  int*      deg      = (int*)alloc(N_NODES * 4);
  int*      loopslot = (int*)alloc(N_NODES * 4);
  int*      srcs     = (int*)alloc((size_t)EP * 4);
  float2*   ea_csr   = (float2*)alloc((size_t)EP * 8);
  float*    asrc     = (float*)alloc(N_NODES * 2 * 4);
  float*    adst     = (float*)alloc(N_NODES * 2 * 4);
  float*    Ae       = (float*)alloc(16 * 4);

  auto cdiv = [](int a, int b) { return (a + b - 1) / b; };

  // graph prep (atomic-minimal): deg histogram -> scan -> scatter -> self-loop attr
  fill_u32<<<cdiv(N_NODES, 256), 256, 0, stream>>>((unsigned*)deg, 1u, N_NODES);
  deg_hist<<<cdiv(N_EDGES, 256), 256, 0, stream>>>(ei, deg);
  scan_deg<<<1, 1024, 0, stream>>>(deg, rowptr, cursor);
  scatter_ea<<<cdiv(EP, 256), 256, 0, stream>>>(ei, ea, cursor, srcs, ea_csr, loopslot);
  lattr_fin<<<cdiv(N_NODES, 256), 256, 0, stream>>>(rowptr, loopslot, ea_csr);

  // operand prep
  prep_ae<<<6, 64, 0, stream>>>(We1, ae1, We2, ae2, Ae);
  bt_split<<<384, 256, 0, stream>>>(W1, W2, B1hi, B1lo, B2hi, B2lo);

  // ---- conv1 (H=2, C=128) ----
  gemm_split<<<dim3(2, cdiv(N_NODES, 64)), 256, 0, stream>>>(x, B1hi, B1lo, xhb, N_NODES, 256);
  node_attn<2><<<N_NODES, 64, 0, stream>>>(xhb, as1, ad1, asrc, adst);
  aggregate_fused<2, 1><<<N_NODES, 256, 0, stream>>>(xhb, asrc, adst, ea_csr, rowptr, srcs,
                                                     Ae, 0, b1, hbuf);

  // ---- conv2 (H=1, C=128) ----
  gemm_split<<<dim3(1, cdiv(N_NODES, 64)), 256, 0, stream>>>(hbuf, B2hi, B2lo, xhb, N_NODES, 128);
  node_attn<1><<<N_NODES, 64, 0, stream>>>(xhb, as2, ad2, asrc, adst);
  aggregate_fused<1, 0><<<N_NODES, 128, 0, stream>>>(xhb, asrc, adst, ea_csr, rowptr, srcs,
                                                     Ae, 4, b2, out);
}

// Round 6
// 398.216 us; speedup vs baseline: 2.8523x; 1.1717x over previous
//
#include <hip/hip_runtime.h>
#include <math.h>

#define N_NODES 50000
#define N_EDGES 800000
#define EP (N_EDGES + N_NODES)   // edges incl. self loops
#define NEG_SLOPE 0.2f

typedef __attribute__((ext_vector_type(8))) short bf16x8;
typedef __attribute__((ext_vector_type(4))) float f32x4;

// ---------- helpers ----------
__device__ __forceinline__ unsigned short f2bf(float f) {
  unsigned u = __float_as_uint(f);
  unsigned r = (u + 0x7FFFu + ((u >> 16) & 1u)) >> 16;
  return (unsigned short)r;
}
__device__ __forceinline__ float bf2f(unsigned short b) {
  return __uint_as_float(((unsigned)b) << 16);
}

__global__ void fill_u32(unsigned* p, unsigned v, int n) {
  int i = blockIdx.x * blockDim.x + threadIdx.x;
  if (i < n) p[i] = v;
}

// ---------- degree histogram: 1 atomic per edge (deg pre-filled to 1 = self loop) ----
__global__ void deg_hist(const int* __restrict__ ei, int* __restrict__ deg) {
  int e = blockIdx.x * blockDim.x + threadIdx.x;
  if (e >= N_EDGES) return;
  atomicAdd(&deg[ei[N_EDGES + e]], 1);
}

// ---------- CSR rowptr: chunked single-block exclusive scan ----------
__global__ void scan_deg(const int* __restrict__ deg, int* __restrict__ rowptr,
                         int* __restrict__ cursor) {
  __shared__ int buf[2][1024];
  const int n = N_NODES;
  const int chunk = (n + 1023) / 1024;
  int lo = threadIdx.x * chunk;
  int hi = lo + chunk; if (hi > n) hi = n;
  int s = 0;
  for (int i = lo; i < hi; ++i) s += deg[i];
  buf[0][threadIdx.x] = s;
  __syncthreads();
  int cur = 0;
  for (int off = 1; off < 1024; off <<= 1) {
    int t = buf[cur][threadIdx.x];
    if ((int)threadIdx.x >= off) t += buf[cur][threadIdx.x - off];
    buf[cur ^ 1][threadIdx.x] = t;
    cur ^= 1;
    __syncthreads();
  }
  int excl = buf[cur][threadIdx.x] - s;
  int run = excl;
  for (int i = lo; i < hi; ++i) {
    rowptr[i] = run; cursor[i] = run;
    run += deg[i];
  }
  if (threadIdx.x == 1023) rowptr[n] = buf[cur][1023];
}

// ---------- scatter edges into CSR slots; ea stored in slot order ----------
__global__ void scatter_ea(const int* __restrict__ ei, const float* __restrict__ ea,
                           int* __restrict__ cursor, int* __restrict__ srcs,
                           float2* __restrict__ ea_csr, int* __restrict__ loopslot) {
  int e = blockIdx.x * blockDim.x + threadIdx.x;
  if (e >= EP) return;
  int s, d; float2 v;
  if (e < N_EDGES) { s = ei[e]; d = ei[N_EDGES + e]; v.x = ea[2 * e]; v.y = ea[2 * e + 1]; }
  else { s = d = e - N_EDGES; v.x = 0.f; v.y = 0.f; }   // self-loop attr filled later
  int pos = atomicAdd(&cursor[d], 1);
  srcs[pos] = s;
  ea_csr[pos] = v;
  if (e >= N_EDGES) loopslot[d] = pos;
}

// ---------- self-loop attr = mean of incoming ea (sequential segment sum) ----------
__global__ void lattr_fin(const int* __restrict__ rowptr, const int* __restrict__ loopslot,
                          float2* __restrict__ ea_csr) {
  int n = blockIdx.x * blockDim.x + threadIdx.x;
  if (n >= N_NODES) return;
  int beg = rowptr[n], end = rowptr[n + 1];
  float s0 = 0.f, s1 = 0.f;
  for (int j = beg; j < end; ++j) {       // loop slot holds (0,0): contributes nothing
    float2 e = ea_csr[j];
    s0 += e.x; s1 += e.y;
  }
  float c = fmaxf((float)(end - beg - 1), 1.0f);
  float2 m; m.x = s0 / c; m.y = s1 / c;
  ea_csr[loopslot[n]] = m;
}

// ---------- Ae[d][h] = sum_c We[d, h*128+c] * att_e[h,c] ----------
__global__ void prep_ae(const float* __restrict__ We1, const float* __restrict__ ae1,
                        const float* __restrict__ We2, const float* __restrict__ ae2,
                        float* __restrict__ Ae) {
  int b = blockIdx.x;
  int t = threadIdx.x;
  float s = 0.f;
  if (b < 4) {
    int d = b >> 1, h = b & 1;
    for (int c = t; c < 128; c += 64)
      s += We1[d * 256 + h * 128 + c] * ae1[h * 128 + c];
  } else {
    int d = b - 4;
    for (int c = t; c < 128; c += 64)
      s += We2[d * 128 + c] * ae2[c];
  }
  for (int off = 32; off > 0; off >>= 1) s += __shfl_down(s, off);
  if (t == 0) Ae[b] = s;   // [d0h0, d0h1, d1h0, d1h1, d0(conv2), d1(conv2)]
}

// ---------- W -> W^T hi/lo split (tiny, cached) ----------
__global__ void bt_split(const float* __restrict__ W1, const float* __restrict__ W2,
                         unsigned short* __restrict__ b1h, unsigned short* __restrict__ b1l,
                         unsigned short* __restrict__ b2h, unsigned short* __restrict__ b2l) {
  int n = blockIdx.x;
  int k = threadIdx.x;   // 256
  float v; unsigned short* ph; unsigned short* pl; int idx;
  if (n < 256) { v = W1[k * 256 + n];       ph = b1h; pl = b1l; idx = n * 256 + k; }
  else         { v = W2[k * 128 + (n - 256)]; ph = b2h; pl = b2l; idx = (n - 256) * 256 + k; }
  unsigned short h = f2bf(v);
  ph[idx] = h;
  pl[idx] = f2bf(v - bf2f(h));
}

// ---------- split-bf16 MFMA GEMM (fp32-accurate) with fused attention epilogue ----
// C_bf16[M,N] = A_f32[M,256] @ B; also asrc[row,h] += C_row . att_src[h] (fp32 acc).
// Block tile 64x128 (one head per bn block), BK=32, 4 waves (2x2), wave 32x64.
template <int H>
__global__ __launch_bounds__(256) void gemm_split(
    const float* __restrict__ A,
    const unsigned short* __restrict__ Bth, const unsigned short* __restrict__ Btl,
    unsigned short* __restrict__ C, int M, int N,
    const float* __restrict__ att_src, const float* __restrict__ att_dst,
    float* __restrict__ asrc, float* __restrict__ adst) {
  __shared__ __attribute__((aligned(16))) unsigned short As[2][64][40];
  __shared__ __attribute__((aligned(16))) unsigned short Bs[2][128][40];
  int bm = blockIdx.y * 64, bn = blockIdx.x * 128;
  int tid = threadIdx.x;
  int l = tid & 63;
  int wid = tid >> 6;
  int wr = wid >> 1, wc = wid & 1;
  int rr = l & 15, kc = l >> 4;

  f32x4 acc[2][4];
  #pragma unroll
  for (int i = 0; i < 2; ++i)
    #pragma unroll
    for (int j = 0; j < 4; ++j)
      acc[i][j] = (f32x4){0.f, 0.f, 0.f, 0.f};

  int ar = tid >> 2, ac = tid & 3;
  int gm = bm + ar;

  for (int kt = 0; kt < 8; ++kt) {
    int k0 = kt * 32;
    float4 f0 = {0.f, 0.f, 0.f, 0.f}, f1 = f0;
    if (gm < M) {
      f0 = *(const float4*)(A + (size_t)gm * 256 + k0 + ac * 8);
      f1 = *(const float4*)(A + (size_t)gm * 256 + k0 + ac * 8 + 4);
    }
    float f[8] = {f0.x, f0.y, f0.z, f0.w, f1.x, f1.y, f1.z, f1.w};
    unsigned hw[4], lw[4];
    #pragma unroll
    for (int q = 0; q < 4; ++q) {
      unsigned short ha = f2bf(f[2 * q]),  hb = f2bf(f[2 * q + 1]);
      unsigned short la = f2bf(f[2 * q] - bf2f(ha)), lb = f2bf(f[2 * q + 1] - bf2f(hb));
      hw[q] = (unsigned)ha | ((unsigned)hb << 16);
      lw[q] = (unsigned)la | ((unsigned)lb << 16);
    }
    *(uint4*)&As[0][ar][ac * 8] = make_uint4(hw[0], hw[1], hw[2], hw[3]);
    *(uint4*)&As[1][ar][ac * 8] = make_uint4(lw[0], lw[1], lw[2], lw[3]);
    #pragma unroll
    for (int p = 0; p < 2; ++p) {
      int id = tid + p * 256;
      int nn = id >> 2, cc = id & 3;
      *(uint4*)&Bs[0][nn][cc * 8] = *(const uint4*)(Bth + (size_t)(bn + nn) * 256 + k0 + cc * 8);
      *(uint4*)&Bs[1][nn][cc * 8] = *(const uint4*)(Btl + (size_t)(bn + nn) * 256 + k0 + cc * 8);
    }
    __syncthreads();
    bf16x8 ah[2], alo[2], bh[4], bl[4];
    #pragma unroll
    for (int i = 0; i < 2; ++i) {
      ah[i]  = *(const bf16x8*)&As[0][wr * 32 + i * 16 + rr][kc * 8];
      alo[i] = *(const bf16x8*)&As[1][wr * 32 + i * 16 + rr][kc * 8];
    }
    #pragma unroll
    for (int j = 0; j < 4; ++j) {
      bh[j] = *(const bf16x8*)&Bs[0][wc * 64 + j * 16 + rr][kc * 8];
      bl[j] = *(const bf16x8*)&Bs[1][wc * 64 + j * 16 + rr][kc * 8];
    }
    #pragma unroll
    for (int i = 0; i < 2; ++i)
      #pragma unroll
      for (int j = 0; j < 4; ++j) {
        acc[i][j] = __builtin_amdgcn_mfma_f32_16x16x32_bf16(ah[i],  bh[j], acc[i][j], 0, 0, 0);
        acc[i][j] = __builtin_amdgcn_mfma_f32_16x16x32_bf16(ah[i],  bl[j], acc[i][j], 0, 0, 0);
        acc[i][j] = __builtin_amdgcn_mfma_f32_16x16x32_bf16(alo[i], bh[j], acc[i][j], 0, 0, 0);
      }
    __syncthreads();
  }

  // C store (bf16)
  #pragma unroll
  for (int i = 0; i < 2; ++i)
    #pragma unroll
    for (int reg = 0; reg < 4; ++reg) {
      int row = bm + wr * 32 + i * 16 + kc * 4 + reg;
      if (row < M) {
        #pragma unroll
        for (int j = 0; j < 4; ++j) {
          int col = bn + wc * 64 + j * 16 + rr;
          C[(size_t)row * N + col] = f2bf(acc[i][j][reg]);
        }
      }
    }

  // fused attention partial dot products (from pre-rounding fp32 acc)
  int head = (H == 2) ? (bn >> 7) : 0;
  float ats[4], atd[4];
  #pragma unroll
  for (int j = 0; j < 4; ++j) {
    int colh = wc * 64 + j * 16 + rr;
    ats[j] = att_src[head * 128 + colh];
    atd[j] = att_dst[head * 128 + colh];
  }
  #pragma unroll
  for (int i = 0; i < 2; ++i)
    #pragma unroll
    for (int reg = 0; reg < 4; ++reg) {
      float sp = acc[i][0][reg] * ats[0] + acc[i][1][reg] * ats[1] +
                 acc[i][2][reg] * ats[2] + acc[i][3][reg] * ats[3];
      float dp = acc[i][0][reg] * atd[0] + acc[i][1][reg] * atd[1] +
                 acc[i][2][reg] * atd[2] + acc[i][3][reg] * atd[3];
      #pragma unroll
      for (int off = 1; off < 16; off <<= 1) {
        sp += __shfl_xor(sp, off);
        dp += __shfl_xor(dp, off);
      }
      int row = bm + wr * 32 + i * 16 + kc * 4 + reg;
      if (rr == 0 && row < M) {
        atomicAdd(&asrc[row * H + head], sp);
        atomicAdd(&adst[row * H + head], dp);
      }
    }
}

// ---------- fused: logits + exp + softmax-denominator + weighted aggregation ------
// One block per node, D/2 threads, 2 packed-bf16 columns per thread, 8-deep unroll.
template <int H, int ACT>
__global__ __launch_bounds__(H * 64)
void aggregate_fused(const unsigned short* __restrict__ xh, const float* __restrict__ asrc,
                     const float* __restrict__ adst, const float2* __restrict__ ea_csr,
                     const int* __restrict__ rowptr, const int* __restrict__ srcs,
                     const float* __restrict__ Ae, int aeoff,
                     const float* __restrict__ bias, float* __restrict__ out) {
  constexpr int D = H * 128;
  constexpr int BD = D / 2;          // threads per block
  constexpr int NW = BD / 64;        // waves per block
  __shared__ float exl[256][H];
  __shared__ int sl[256];
  __shared__ float wred[NW * H];
  __shared__ float totsum[H];
  int n = blockIdx.x;
  int t = threadIdx.x;
  int beg = rowptr[n], end = rowptr[n + 1];
  int hA = t & (H - 1);                 // phase-A head (fixed per thread)
  float adnA = adst[n * H + hA];
  float Ae0 = Ae[aeoff + hA], Ae1 = Ae[aeoff + H + hA];
  int hB = (H == 2) ? (t >> 6) : 0;     // phase-B head (cols 2t,2t+1)
  float lsum = 0.f;
  float accA[4] = {0.f, 0.f, 0.f, 0.f}, accB[4] = {0.f, 0.f, 0.f, 0.f};

  for (int cbeg = beg; cbeg < end; cbeg += 256) {
    int cnt = min(256, end - cbeg);
    for (int idx = t; idx < cnt * H; idx += BD) {
      int j0 = idx / H;
      int jj = cbeg + j0;
      int s = srcs[jj];
      float2 e = ea_csr[jj];
      float lg = asrc[s * H + hA] + adnA + e.x * Ae0 + e.y * Ae1;
      lg = (lg > 0.f) ? lg : NEG_SLOPE * lg;
      float ex = __expf(lg);
      exl[j0][hA] = ex;
      if (hA == 0) sl[j0] = s;
      lsum += ex;
    }
    __syncthreads();
    int j = 0;
    for (; j + 8 <= cnt; j += 8) {
      #pragma unroll
      for (int q = 0; q < 8; ++q) {
        float e = exl[j + q][hB];
        int s = sl[j + q];
        unsigned u = *(const unsigned*)(xh + (size_t)s * D + 2 * t);
        accA[q & 3] = fmaf(e, __uint_as_float(u << 16), accA[q & 3]);
        accB[q & 3] = fmaf(e, __uint_as_float(u & 0xFFFF0000u), accB[q & 3]);
      }
    }
    for (; j < cnt; ++j) {
      float e = exl[j][hB];
      int s = sl[j];
      unsigned u = *(const unsigned*)(xh + (size_t)s * D + 2 * t);
      accA[0] = fmaf(e, __uint_as_float(u << 16), accA[0]);
      accB[0] = fmaf(e, __uint_as_float(u & 0xFFFF0000u), accB[0]);
    }
    __syncthreads();
  }

  // block-reduce lsum per head class (parity classes of width H within each wave)
  #pragma unroll
  for (int off = H; off < 64; off <<= 1) lsum += __shfl_xor(lsum, off);
  int lane = t & 63, wid = t >> 6;
  if (lane < H) wred[wid * H + lane] = lsum;
  __syncthreads();
  if (t < H) {
    float tot = 0.f;
    for (int wv = 0; wv < NW; ++wv) tot += wred[wv * H + t];
    totsum[t] = tot;
  }
  __syncthreads();
  float inv = 1.0f / (totsum[hB] + 1e-16f);
  float v0 = fmaf(inv, (accA[0] + accA[1]) + (accA[2] + accA[3]), bias[2 * t]);
  float v1 = fmaf(inv, (accB[0] + accB[1]) + (accB[2] + accB[3]), bias[2 * t + 1]);
  if (ACT) {
    v0 = (v0 > 0.f) ? v0 : expm1f(v0);
    v1 = (v1 > 0.f) ? v1 : expm1f(v1);
  }
  *(float2*)(out + (size_t)n * D + 2 * t) = make_float2(v0, v1);
}

// ---------- launch ----------
extern "C" void kernel_launch(void* const* d_in, const int* in_sizes, int n_in,
                              void* d_out, int out_size, void* d_ws, size_t ws_size,
                              hipStream_t stream) {
  const float* x    = (const float*)d_in[0];
  const int*   ei   = (const int*)d_in[1];
  const float* ea   = (const float*)d_in[2];
  const float* W1   = (const float*)d_in[3];
  const float* as1  = (const float*)d_in[4];
  const float* ad1  = (const float*)d_in[5];
  const float* We1  = (const float*)d_in[6];
  const float* ae1  = (const float*)d_in[7];
  const float* b1   = (const float*)d_in[8];
  const float* W2   = (const float*)d_in[9];
  const float* as2  = (const float*)d_in[10];
  const float* ad2  = (const float*)d_in[11];
  const float* We2  = (const float*)d_in[12];
  const float* ae2  = (const float*)d_in[13];
  const float* b2   = (const float*)d_in[14];
  float* out = (float*)d_out;

  char* w = (char*)d_ws;
  size_t off = 0;
  auto alloc = [&](size_t bytes) -> void* {
    void* p = w + off;
    off = (off + bytes + 255) & ~(size_t)255;
    return p;
  };
  unsigned short* xhb   = (unsigned short*)alloc((size_t)N_NODES * 256 * 2); // bf16 conv outputs
  float*          hbuf  = (float*)alloc((size_t)N_NODES * 256 * 4);          // conv1 aggregate (fp32)
  unsigned short* B1hi  = (unsigned short*)alloc(256 * 256 * 2);
  unsigned short* B1lo  = (unsigned short*)alloc(256 * 256 * 2);
  unsigned short* B2hi  = (unsigned short*)alloc(128 * 256 * 2);
  unsigned short* B2lo  = (unsigned short*)alloc(128 * 256 * 2);
  int*      rowptr   = (int*)alloc((N_NODES + 1) * 4);
  int*      cursor   = (int*)alloc(N_NODES * 4);
  int*      deg      = (int*)alloc(N_NODES * 4);
  int*      loopslot = (int*)alloc(N_NODES * 4);
  int*      srcs     = (int*)alloc((size_t)EP * 4);
  float2*   ea_csr   = (float2*)alloc((size_t)EP * 8);
  float*    asrc     = (float*)alloc(N_NODES * 2 * 4);
  float*    adst     = (float*)alloc(N_NODES * 2 * 4);
  float*    Ae       = (float*)alloc(16 * 4);

  auto cdiv = [](int a, int b) { return (a + b - 1) / b; };

  // graph prep (atomic-minimal): deg histogram -> scan -> scatter -> self-loop attr
  fill_u32<<<cdiv(N_NODES, 256), 256, 0, stream>>>((unsigned*)deg, 1u, N_NODES);
  deg_hist<<<cdiv(N_EDGES, 256), 256, 0, stream>>>(ei, deg);
  scan_deg<<<1, 1024, 0, stream>>>(deg, rowptr, cursor);
  scatter_ea<<<cdiv(EP, 256), 256, 0, stream>>>(ei, ea, cursor, srcs, ea_csr, loopslot);
  lattr_fin<<<cdiv(N_NODES, 256), 256, 0, stream>>>(rowptr, loopslot, ea_csr);

  // operand prep
  prep_ae<<<6, 64, 0, stream>>>(We1, ae1, We2, ae2, Ae);
  bt_split<<<384, 256, 0, stream>>>(W1, W2, B1hi, B1lo, B2hi, B2lo);

  // ---- conv1 (H=2, C=128) ----
  fill_u32<<<cdiv(N_NODES * 4, 256), 256, 0, stream>>>((unsigned*)asrc, 0u, N_NODES * 2);
  fill_u32<<<cdiv(N_NODES * 4, 256), 256, 0, stream>>>((unsigned*)adst, 0u, N_NODES * 2);
  gemm_split<2><<<dim3(2, cdiv(N_NODES, 64)), 256, 0, stream>>>(x, B1hi, B1lo, xhb, N_NODES, 256,
                                                                as1, ad1, asrc, adst);
  aggregate_fused<2, 1><<<N_NODES, 128, 0, stream>>>(xhb, asrc, adst, ea_csr, rowptr, srcs,
                                                     Ae, 0, b1, hbuf);

  // ---- conv2 (H=1, C=128) ----
  fill_u32<<<cdiv(N_NODES, 256), 256, 0, stream>>>((unsigned*)asrc, 0u, N_NODES);
  fill_u32<<<cdiv(N_NODES, 256), 256, 0, stream>>>((unsigned*)adst, 0u, N_NODES);
  gemm_split<1><<<dim3(1, cdiv(N_NODES, 64)), 256, 0, stream>>>(hbuf, B2hi, B2lo, xhb, N_NODES, 128,
                                                                as2, ad2, asrc, adst);
  aggregate_fused<1, 0><<<N_NODES, 64, 0, stream>>>(xhb, asrc, adst, ea_csr, rowptr, srcs,
                                                    Ae, 4, b2, out);
}

// Round 7
// 295.026 us; speedup vs baseline: 3.8500x; 1.3498x over previous
//
#include <hip/hip_runtime.h>
#include <math.h>

#define N_NODES 50000
#define N_EDGES 800000
#define EP (N_EDGES + N_NODES)   // edges incl. self loops
#define NEG_SLOPE 0.2f
#define SCAN_BLOCKS ((N_NODES + 255) / 256)   // 196

typedef __attribute__((ext_vector_type(8))) short bf16x8;
typedef __attribute__((ext_vector_type(4))) float f32x4;

// ---------- helpers ----------
__device__ __forceinline__ unsigned short f2bf(float f) {
  unsigned u = __float_as_uint(f);
  unsigned r = (u + 0x7FFFu + ((u >> 16) & 1u)) >> 16;
  return (unsigned short)r;
}
__device__ __forceinline__ float bf2f(unsigned short b) {
  return __uint_as_float(((unsigned)b) << 16);
}

__global__ void fill_u32(unsigned* p, unsigned v, int n) {
  int i = blockIdx.x * blockDim.x + threadIdx.x;
  if (i < n) p[i] = v;
}

// ---------- degree histogram: 1 atomic per edge (deg pre-filled to 1 = self loop) ----
__global__ void deg_hist(const int* __restrict__ ei, int* __restrict__ deg) {
  int e = blockIdx.x * blockDim.x + threadIdx.x;
  if (e >= N_EDGES) return;
  atomicAdd(&deg[ei[N_EDGES + e]], 1);
}

// ---------- multi-block exclusive scan of deg -> rowptr (3 small kernels) ----------
__global__ void block_sums(const int* __restrict__ deg, int* __restrict__ bsum) {
  __shared__ int ws[4];
  int b = blockIdx.x;
  int i = b * 256 + threadIdx.x;
  int v = (i < N_NODES) ? deg[i] : 0;
  #pragma unroll
  for (int off = 32; off > 0; off >>= 1) v += __shfl_down(v, off);
  if ((threadIdx.x & 63) == 0) ws[threadIdx.x >> 6] = v;
  __syncthreads();
  if (threadIdx.x == 0) bsum[b] = ws[0] + ws[1] + ws[2] + ws[3];
}

__global__ void scan_bsum(const int* __restrict__ bsum, int* __restrict__ boff) {
  __shared__ int buf[2][256];
  int t = threadIdx.x;
  int v = (t < SCAN_BLOCKS) ? bsum[t] : 0;
  buf[0][t] = v;
  __syncthreads();
  int cur = 0;
  for (int off = 1; off < 256; off <<= 1) {
    int x = buf[cur][t];
    if (t >= off) x += buf[cur][t - off];
    buf[cur ^ 1][t] = x;
    cur ^= 1;
    __syncthreads();
  }
  boff[t] = buf[cur][t] - v;   // exclusive prefix of block sums
}

__global__ void emit_rowptr(const int* __restrict__ deg, const int* __restrict__ boff,
                            int* __restrict__ rowptr, int* __restrict__ cursor) {
  __shared__ int buf[2][256];
  int b = blockIdx.x;
  int t = threadIdx.x;
  int i = b * 256 + t;
  int v = (i < N_NODES) ? deg[i] : 0;
  buf[0][t] = v;
  __syncthreads();
  int cur = 0;
  for (int off = 1; off < 256; off <<= 1) {
    int x = buf[cur][t];
    if (t >= off) x += buf[cur][t - off];
    buf[cur ^ 1][t] = x;
    cur ^= 1;
    __syncthreads();
  }
  int incl = buf[cur][t];
  int base = boff[b];
  if (i < N_NODES) {
    int r = base + incl - v;
    rowptr[i] = r;
    cursor[i] = r;
    if (i == N_NODES - 1) rowptr[N_NODES] = base + incl;
  }
}

// ---------- scatter edges into CSR slots; ea stored in slot order ----------
__global__ void scatter_ea(const int* __restrict__ ei, const float* __restrict__ ea,
                           int* __restrict__ cursor, int* __restrict__ srcs,
                           float2* __restrict__ ea_csr, int* __restrict__ loopslot) {
  int e = blockIdx.x * blockDim.x + threadIdx.x;
  if (e >= EP) return;
  int s, d; float2 v;
  if (e < N_EDGES) { s = ei[e]; d = ei[N_EDGES + e]; v.x = ea[2 * e]; v.y = ea[2 * e + 1]; }
  else { s = d = e - N_EDGES; v.x = 0.f; v.y = 0.f; }   // self-loop attr filled later
  int pos = atomicAdd(&cursor[d], 1);
  srcs[pos] = s;
  ea_csr[pos] = v;
  if (e >= N_EDGES) loopslot[d] = pos;
}

// ---------- self-loop attr = mean of incoming ea (sequential segment sum) ----------
__global__ void lattr_fin(const int* __restrict__ rowptr, const int* __restrict__ loopslot,
                          float2* __restrict__ ea_csr) {
  int n = blockIdx.x * blockDim.x + threadIdx.x;
  if (n >= N_NODES) return;
  int beg = rowptr[n], end = rowptr[n + 1];
  float s0 = 0.f, s1 = 0.f;
  for (int j = beg; j < end; ++j) {       // loop slot holds (0,0): contributes nothing
    float2 e = ea_csr[j];
    s0 += e.x; s1 += e.y;
  }
  float c = fmaxf((float)(end - beg - 1), 1.0f);
  float2 m; m.x = s0 / c; m.y = s1 / c;
  ea_csr[loopslot[n]] = m;
}

// ---------- Ae[d][h] = sum_c We[d, h*128+c] * att_e[h,c] ----------
__global__ void prep_ae(const float* __restrict__ We1, const float* __restrict__ ae1,
                        const float* __restrict__ We2, const float* __restrict__ ae2,
                        float* __restrict__ Ae) {
  int b = blockIdx.x;
  int t = threadIdx.x;
  float s = 0.f;
  if (b < 4) {
    int d = b >> 1, h = b & 1;
    for (int c = t; c < 128; c += 64)
      s += We1[d * 256 + h * 128 + c] * ae1[h * 128 + c];
  } else {
    int d = b - 4;
    for (int c = t; c < 128; c += 64)
      s += We2[d * 128 + c] * ae2[c];
  }
  for (int off = 32; off > 0; off >>= 1) s += __shfl_down(s, off);
  if (t == 0) Ae[b] = s;   // [d0h0, d0h1, d1h0, d1h1, d0(conv2), d1(conv2)]
}

// ---------- W -> W^T hi/lo split (tiny, cached) ----------
__global__ void bt_split(const float* __restrict__ W1, const float* __restrict__ W2,
                         unsigned short* __restrict__ b1h, unsigned short* __restrict__ b1l,
                         unsigned short* __restrict__ b2h, unsigned short* __restrict__ b2l) {
  int n = blockIdx.x;
  int k = threadIdx.x;   // 256
  float v; unsigned short* ph; unsigned short* pl; int idx;
  if (n < 256) { v = W1[k * 256 + n];       ph = b1h; pl = b1l; idx = n * 256 + k; }
  else         { v = W2[k * 128 + (n - 256)]; ph = b2h; pl = b2l; idx = (n - 256) * 256 + k; }
  unsigned short h = f2bf(v);
  ph[idx] = h;
  pl[idx] = f2bf(v - bf2f(h));
}

// ---------- split-bf16 MFMA GEMM (fp32-accurate) with fused attention epilogue ----
// C_bf16[M,N] = A_f32[M,256] @ B; also asrc[row,h] += C_row . att_src[h] (fp32 acc).
// Block tile 64x128 (one head per bn block), BK=32, 4 waves (2x2), wave 32x64.
template <int H>
__global__ __launch_bounds__(256) void gemm_split(
    const float* __restrict__ A,
    const unsigned short* __restrict__ Bth, const unsigned short* __restrict__ Btl,
    unsigned short* __restrict__ C, int M, int N,
    const float* __restrict__ att_src, const float* __restrict__ att_dst,
    float* __restrict__ asrc, float* __restrict__ adst) {
  __shared__ __attribute__((aligned(16))) unsigned short As[2][64][40];
  __shared__ __attribute__((aligned(16))) unsigned short Bs[2][128][40];
  int bm = blockIdx.y * 64, bn = blockIdx.x * 128;
  int tid = threadIdx.x;
  int l = tid & 63;
  int wid = tid >> 6;
  int wr = wid >> 1, wc = wid & 1;
  int rr = l & 15, kc = l >> 4;

  f32x4 acc[2][4];
  #pragma unroll
  for (int i = 0; i < 2; ++i)
    #pragma unroll
    for (int j = 0; j < 4; ++j)
      acc[i][j] = (f32x4){0.f, 0.f, 0.f, 0.f};

  int ar = tid >> 2, ac = tid & 3;
  int gm = bm + ar;

  for (int kt = 0; kt < 8; ++kt) {
    int k0 = kt * 32;
    float4 f0 = {0.f, 0.f, 0.f, 0.f}, f1 = f0;
    if (gm < M) {
      f0 = *(const float4*)(A + (size_t)gm * 256 + k0 + ac * 8);
      f1 = *(const float4*)(A + (size_t)gm * 256 + k0 + ac * 8 + 4);
    }
    float f[8] = {f0.x, f0.y, f0.z, f0.w, f1.x, f1.y, f1.z, f1.w};
    unsigned hw[4], lw[4];
    #pragma unroll
    for (int q = 0; q < 4; ++q) {
      unsigned short ha = f2bf(f[2 * q]),  hb = f2bf(f[2 * q + 1]);
      unsigned short la = f2bf(f[2 * q] - bf2f(ha)), lb = f2bf(f[2 * q + 1] - bf2f(hb));
      hw[q] = (unsigned)ha | ((unsigned)hb << 16);
      lw[q] = (unsigned)la | ((unsigned)lb << 16);
    }
    *(uint4*)&As[0][ar][ac * 8] = make_uint4(hw[0], hw[1], hw[2], hw[3]);
    *(uint4*)&As[1][ar][ac * 8] = make_uint4(lw[0], lw[1], lw[2], lw[3]);
    #pragma unroll
    for (int p = 0; p < 2; ++p) {
      int id = tid + p * 256;
      int nn = id >> 2, cc = id & 3;
      *(uint4*)&Bs[0][nn][cc * 8] = *(const uint4*)(Bth + (size_t)(bn + nn) * 256 + k0 + cc * 8);
      *(uint4*)&Bs[1][nn][cc * 8] = *(const uint4*)(Btl + (size_t)(bn + nn) * 256 + k0 + cc * 8);
    }
    __syncthreads();
    bf16x8 ah[2], alo[2], bh[4], bl[4];
    #pragma unroll
    for (int i = 0; i < 2; ++i) {
      ah[i]  = *(const bf16x8*)&As[0][wr * 32 + i * 16 + rr][kc * 8];
      alo[i] = *(const bf16x8*)&As[1][wr * 32 + i * 16 + rr][kc * 8];
    }
    #pragma unroll
    for (int j = 0; j < 4; ++j) {
      bh[j] = *(const bf16x8*)&Bs[0][wc * 64 + j * 16 + rr][kc * 8];
      bl[j] = *(const bf16x8*)&Bs[1][wc * 64 + j * 16 + rr][kc * 8];
    }
    #pragma unroll
    for (int i = 0; i < 2; ++i)
      #pragma unroll
      for (int j = 0; j < 4; ++j) {
        acc[i][j] = __builtin_amdgcn_mfma_f32_16x16x32_bf16(ah[i],  bh[j], acc[i][j], 0, 0, 0);
        acc[i][j] = __builtin_amdgcn_mfma_f32_16x16x32_bf16(ah[i],  bl[j], acc[i][j], 0, 0, 0);
        acc[i][j] = __builtin_amdgcn_mfma_f32_16x16x32_bf16(alo[i], bh[j], acc[i][j], 0, 0, 0);
      }
    __syncthreads();
  }

  // C store (bf16)
  #pragma unroll
  for (int i = 0; i < 2; ++i)
    #pragma unroll
    for (int reg = 0; reg < 4; ++reg) {
      int row = bm + wr * 32 + i * 16 + kc * 4 + reg;
      if (row < M) {
        #pragma unroll
        for (int j = 0; j < 4; ++j) {
          int col = bn + wc * 64 + j * 16 + rr;
          C[(size_t)row * N + col] = f2bf(acc[i][j][reg]);
        }
      }
    }

  // fused attention partial dot products (from pre-rounding fp32 acc)
  int head = (H == 2) ? (bn >> 7) : 0;
  float ats[4], atd[4];
  #pragma unroll
  for (int j = 0; j < 4; ++j) {
    int colh = wc * 64 + j * 16 + rr;
    ats[j] = att_src[head * 128 + colh];
    atd[j] = att_dst[head * 128 + colh];
  }
  #pragma unroll
  for (int i = 0; i < 2; ++i)
    #pragma unroll
    for (int reg = 0; reg < 4; ++reg) {
      float sp = acc[i][0][reg] * ats[0] + acc[i][1][reg] * ats[1] +
                 acc[i][2][reg] * ats[2] + acc[i][3][reg] * ats[3];
      float dp = acc[i][0][reg] * atd[0] + acc[i][1][reg] * atd[1] +
                 acc[i][2][reg] * atd[2] + acc[i][3][reg] * atd[3];
      #pragma unroll
      for (int off = 1; off < 16; off <<= 1) {
        sp += __shfl_xor(sp, off);
        dp += __shfl_xor(dp, off);
      }
      int row = bm + wr * 32 + i * 16 + kc * 4 + reg;
      if (rr == 0 && row < M) {
        atomicAdd(&asrc[row * H + head], sp);
        atomicAdd(&adst[row * H + head], dp);
      }
    }
}

// ---------- fused: logits + exp + softmax-denominator + weighted aggregation ------
// One block per node, D/2 threads, 2 packed-bf16 columns per thread, 8-deep unroll.
template <int H, int ACT>
__global__ __launch_bounds__(H * 64)
void aggregate_fused(const unsigned short* __restrict__ xh, const float* __restrict__ asrc,
                     const float* __restrict__ adst, const float2* __restrict__ ea_csr,
                     const int* __restrict__ rowptr, const int* __restrict__ srcs,
                     const float* __restrict__ Ae, int aeoff,
                     const float* __restrict__ bias, float* __restrict__ out) {
  constexpr int D = H * 128;
  constexpr int BD = D / 2;          // threads per block
  constexpr int NW = BD / 64;        // waves per block
  __shared__ float exl[256][H];
  __shared__ int sl[256];
  __shared__ float wred[NW * H];
  __shared__ float totsum[H];
  int n = blockIdx.x;
  int t = threadIdx.x;
  int beg = rowptr[n], end = rowptr[n + 1];
  int hA = t & (H - 1);                 // phase-A head (fixed per thread)
  float adnA = adst[n * H + hA];
  float Ae0 = Ae[aeoff + hA], Ae1 = Ae[aeoff + H + hA];
  int hB = (H == 2) ? (t >> 6) : 0;     // phase-B head (cols 2t,2t+1)
  float lsum = 0.f;
  float accA[4] = {0.f, 0.f, 0.f, 0.f}, accB[4] = {0.f, 0.f, 0.f, 0.f};

  for (int cbeg = beg; cbeg < end; cbeg += 256) {
    int cnt = min(256, end - cbeg);
    for (int idx = t; idx < cnt * H; idx += BD) {
      int j0 = idx / H;
      int jj = cbeg + j0;
      int s = srcs[jj];
      float2 e = ea_csr[jj];
      float lg = asrc[s * H + hA] + adnA + e.x * Ae0 + e.y * Ae1;
      lg = (lg > 0.f) ? lg : NEG_SLOPE * lg;
      float ex = __expf(lg);
      exl[j0][hA] = ex;
      if (hA == 0) sl[j0] = s;
      lsum += ex;
    }
    __syncthreads();
    int j = 0;
    for (; j + 8 <= cnt; j += 8) {
      #pragma unroll
      for (int q = 0; q < 8; ++q) {
        float e = exl[j + q][hB];
        int s = sl[j + q];
        unsigned u = *(const unsigned*)(xh + (size_t)s * D + 2 * t);
        accA[q & 3] = fmaf(e, __uint_as_float(u << 16), accA[q & 3]);
        accB[q & 3] = fmaf(e, __uint_as_float(u & 0xFFFF0000u), accB[q & 3]);
      }
    }
    for (; j < cnt; ++j) {
      float e = exl[j][hB];
      int s = sl[j];
      unsigned u = *(const unsigned*)(xh + (size_t)s * D + 2 * t);
      accA[0] = fmaf(e, __uint_as_float(u << 16), accA[0]);
      accB[0] = fmaf(e, __uint_as_float(u & 0xFFFF0000u), accB[0]);
    }
    __syncthreads();
  }

  // block-reduce lsum per head class (parity classes of width H within each wave)
  #pragma unroll
  for (int off = H; off < 64; off <<= 1) lsum += __shfl_xor(lsum, off);
  int lane = t & 63, wid = t >> 6;
  if (lane < H) wred[wid * H + lane] = lsum;
  __syncthreads();
  if (t < H) {
    float tot = 0.f;
    for (int wv = 0; wv < NW; ++wv) tot += wred[wv * H + t];
    totsum[t] = tot;
  }
  __syncthreads();
  float inv = 1.0f / (totsum[hB] + 1e-16f);
  float v0 = fmaf(inv, (accA[0] + accA[1]) + (accA[2] + accA[3]), bias[2 * t]);
  float v1 = fmaf(inv, (accB[0] + accB[1]) + (accB[2] + accB[3]), bias[2 * t + 1]);
  if (ACT) {
    v0 = (v0 > 0.f) ? v0 : expm1f(v0);
    v1 = (v1 > 0.f) ? v1 : expm1f(v1);
  }
  *(float2*)(out + (size_t)n * D + 2 * t) = make_float2(v0, v1);
}

// ---------- launch ----------
extern "C" void kernel_launch(void* const* d_in, const int* in_sizes, int n_in,
                              void* d_out, int out_size, void* d_ws, size_t ws_size,
                              hipStream_t stream) {
  const float* x    = (const float*)d_in[0];
  const int*   ei   = (const int*)d_in[1];
  const float* ea   = (const float*)d_in[2];
  const float* W1   = (const float*)d_in[3];
  const float* as1  = (const float*)d_in[4];
  const float* ad1  = (const float*)d_in[5];
  const float* We1  = (const float*)d_in[6];
  const float* ae1  = (const float*)d_in[7];
  const float* b1   = (const float*)d_in[8];
  const float* W2   = (const float*)d_in[9];
  const float* as2  = (const float*)d_in[10];
  const float* ad2  = (const float*)d_in[11];
  const float* We2  = (const float*)d_in[12];
  const float* ae2  = (const float*)d_in[13];
  const float* b2   = (const float*)d_in[14];
  float* out = (float*)d_out;

  char* w = (char*)d_ws;
  size_t off = 0;
  auto alloc = [&](size_t bytes) -> void* {
    void* p = w + off;
    off = (off + bytes + 255) & ~(size_t)255;
    return p;
  };
  unsigned short* xhb   = (unsigned short*)alloc((size_t)N_NODES * 256 * 2); // bf16 conv outputs
  float*          hbuf  = (float*)alloc((size_t)N_NODES * 256 * 4);          // conv1 aggregate (fp32)
  unsigned short* B1hi  = (unsigned short*)alloc(256 * 256 * 2);
  unsigned short* B1lo  = (unsigned short*)alloc(256 * 256 * 2);
  unsigned short* B2hi  = (unsigned short*)alloc(128 * 256 * 2);
  unsigned short* B2lo  = (unsigned short*)alloc(128 * 256 * 2);
  int*      rowptr   = (int*)alloc((N_NODES + 1) * 4);
  int*      cursor   = (int*)alloc(N_NODES * 4);
  int*      deg      = (int*)alloc(N_NODES * 4);
  int*      loopslot = (int*)alloc(N_NODES * 4);
  int*      bsum     = (int*)alloc(256 * 4);
  int*      boff     = (int*)alloc(256 * 4);
  int*      srcs     = (int*)alloc((size_t)EP * 4);
  float2*   ea_csr   = (float2*)alloc((size_t)EP * 8);
  float*    asrc     = (float*)alloc(N_NODES * 2 * 4);
  float*    adst     = (float*)alloc(N_NODES * 2 * 4);
  float*    Ae       = (float*)alloc(16 * 4);

  auto cdiv = [](int a, int b) { return (a + b - 1) / b; };

  // graph prep (atomic-minimal): deg histogram -> 3-phase scan -> scatter -> loop attr
  fill_u32<<<cdiv(N_NODES, 256), 256, 0, stream>>>((unsigned*)deg, 1u, N_NODES);
  deg_hist<<<cdiv(N_EDGES, 256), 256, 0, stream>>>(ei, deg);
  block_sums<<<SCAN_BLOCKS, 256, 0, stream>>>(deg, bsum);
  scan_bsum<<<1, 256, 0, stream>>>(bsum, boff);
  emit_rowptr<<<SCAN_BLOCKS, 256, 0, stream>>>(deg, boff, rowptr, cursor);
  scatter_ea<<<cdiv(EP, 256), 256, 0, stream>>>(ei, ea, cursor, srcs, ea_csr, loopslot);
  lattr_fin<<<cdiv(N_NODES, 256), 256, 0, stream>>>(rowptr, loopslot, ea_csr);

  // operand prep
  prep_ae<<<6, 64, 0, stream>>>(We1, ae1, We2, ae2, Ae);
  bt_split<<<384, 256, 0, stream>>>(W1, W2, B1hi, B1lo, B2hi, B2lo);

  // ---- conv1 (H=2, C=128) ----
  fill_u32<<<cdiv(N_NODES * 2, 256), 256, 0, stream>>>((unsigned*)asrc, 0u, N_NODES * 2);
  fill_u32<<<cdiv(N_NODES * 2, 256), 256, 0, stream>>>((unsigned*)adst, 0u, N_NODES * 2);
  gemm_split<2><<<dim3(2, cdiv(N_NODES, 64)), 256, 0, stream>>>(x, B1hi, B1lo, xhb, N_NODES, 256,
                                                                as1, ad1, asrc, adst);
  aggregate_fused<2, 1><<<N_NODES, 128, 0, stream>>>(xhb, asrc, adst, ea_csr, rowptr, srcs,
                                                     Ae, 0, b1, hbuf);

  // ---- conv2 (H=1, C=128) ----
  fill_u32<<<cdiv(N_NODES, 256), 256, 0, stream>>>((unsigned*)asrc, 0u, N_NODES);
  fill_u32<<<cdiv(N_NODES, 256), 256, 0, stream>>>((unsigned*)adst, 0u, N_NODES);
  gemm_split<1><<<dim3(1, cdiv(N_NODES, 64)), 256, 0, stream>>>(hbuf, B2hi, B2lo, xhb, N_NODES, 128,
                                                                as2, ad2, asrc, adst);
  aggregate_fused<1, 0><<<N_NODES, 64, 0, stream>>>(xhb, asrc, adst, ea_csr, rowptr, srcs,
                                                    Ae, 4, b2, out);
}